// Round 1
// baseline (3086.806 us; speedup 1.0000x reference)
//
#include <hip/hip_runtime.h>

#define T_LEN 131072
#define RD 32
#define SD 512
#define QD 256
#define NL 27
#define KTOT (NL * RD)   // 864

typedef __attribute__((ext_vector_type(8))) short short8;
typedef __attribute__((ext_vector_type(4))) float floatx4;

__device__ __forceinline__ unsigned short f2bf(float f) {
    union { float f; unsigned int i; } v; v.f = f;
    unsigned int r = v.i + 0x7fffu + ((v.i >> 16) & 1u);  // RNE
    return (unsigned short)(r >> 16);
}
__device__ __forceinline__ float bf2f(unsigned short u) {
    union { unsigned int i; float f; } v; v.i = ((unsigned int)u) << 16; return v.f;
}

// ---------------- initial conv: [1,T] -> [32,T], k=3, pad=1 ----------------
__global__ __launch_bounds__(256)
void k_conv_init(const float* __restrict__ x, const float* __restrict__ Wc,
                 const float* __restrict__ bc, float* __restrict__ xout)
{
    const int t = blockIdx.x * 256 + threadIdx.x;
    const float xm = (t > 0) ? x[t - 1] : 0.f;
    const float x0 = x[t];
    const float xp = (t < T_LEN - 1) ? x[t + 1] : 0.f;
#pragma unroll
    for (int o = 0; o < RD; ++o) {
        xout[(size_t)o * T_LEN + t] =
            bc[o] + Wc[o * 3 + 0] * xm + Wc[o * 3 + 1] * x0 + Wc[o * 3 + 2] * xp;
    }
}

// ---------------- one residual layer (fp32) ----------------
// g = tanh(Wt *d x + bt) * sigmoid(Ws *d x + bs)
// Gt[t][layer*32+o] = bf16(g[o])
// xout = Wd @ g + bd + xin
__global__ __launch_bounds__(256, 2)
void k_layer(const float* __restrict__ xin, float* __restrict__ xout,
             unsigned short* __restrict__ Gt,
             const float* __restrict__ Wt, const float* __restrict__ bt,
             const float* __restrict__ Ws, const float* __restrict__ bs,
             const float* __restrict__ Wd, const float* __restrict__ bd,
             int d, int layer)
{
    const int t = blockIdx.x * 256 + threadIdx.x;
    float aT[RD], aS[RD];
#pragma unroll
    for (int o = 0; o < RD; ++o) { aT[o] = bt[o]; aS[o] = bs[o]; }

    const bool okm = (t >= d);
    const bool okp = (t + d < T_LEN);
    for (int c = 0; c < RD; ++c) {
        const float* xr = xin + (size_t)c * T_LEN + t;
        const float xm = okm ? xr[-d] : 0.f;
        const float x0 = xr[0];
        const float xp = okp ? xr[d] : 0.f;
        const float* wt = Wt + c * 3;
        const float* ws = Ws + c * 3;
#pragma unroll
        for (int o = 0; o < RD; ++o) {
            aT[o] += wt[o * 96 + 0] * xm + wt[o * 96 + 1] * x0 + wt[o * 96 + 2] * xp;
            aS[o] += ws[o * 96 + 0] * xm + ws[o * 96 + 1] * x0 + ws[o * 96 + 2] * xp;
        }
    }

    float g[RD];
    unsigned short* gt = Gt + (size_t)t * KTOT + layer * RD;
#pragma unroll
    for (int o = 0; o < RD; ++o) {
        const float e2 = __expf(2.f * aT[o]);
        const float th = 1.f - __fdividef(2.f, e2 + 1.f);
        const float sg = __fdividef(1.f, 1.f + __expf(-aS[o]));
        g[o] = th * sg;
        gt[o] = f2bf(g[o]);
    }

#pragma unroll
    for (int o = 0; o < RD; ++o) {
        float s = bd[o] + xin[(size_t)o * T_LEN + t];
        const float* wd = Wd + o * RD;
#pragma unroll
        for (int c = 0; c < RD; ++c) s += wd[c] * g[c];
        xout[(size_t)o * T_LEN + t] = s;
    }
}

// ---------------- Wcomb[m][k] = sum_j Wp1[m][j] * Wskip[l][j][c], k=l*32+c ----------------
__global__ __launch_bounds__(256)
void k_wcomb(const float* __restrict__ Wp1, const float* __restrict__ Wskip,
             unsigned short* __restrict__ Wcomb)
{
    const int idx = blockIdx.x * 256 + threadIdx.x;
    if (idx >= SD * KTOT) return;
    const int m = idx / KTOT;
    const int k = idx % KTOT;
    const int l = k / RD;
    const int c = k % RD;
    const float* wp1r = Wp1 + (size_t)m * SD;
    const float* wsk = Wskip + (size_t)l * SD * RD + c;
    float acc = 0.f;
    for (int j = 0; j < SD; ++j) acc += wp1r[j] * wsk[(size_t)j * RD];
    Wcomb[idx] = f2bf(acc);
}

// ---------------- hbias[m] = bp1[m] + sum_j Wp1[m][j] * (sum_l bskip[l][j]) ----------------
__global__ __launch_bounds__(512)
void k_hbias(const float* __restrict__ Wp1, const float* __restrict__ bp1,
             const float* __restrict__ bskip, float* __restrict__ hbias)
{
    __shared__ float sb[SD];
    const int tid = threadIdx.x;
    float s = 0.f;
    for (int l = 0; l < NL; ++l) s += bskip[l * SD + tid];
    sb[tid] = s;
    __syncthreads();
    float acc = bp1[tid];
    const float* r = Wp1 + (size_t)tid * SD;
    for (int j = 0; j < SD; ++j) acc += r[j] * sb[j];
    hbias[tid] = acc;
}

// ---------------- fp32 -> bf16 cast ----------------
__global__ __launch_bounds__(256)
void k_cvt(const float* __restrict__ src, unsigned short* __restrict__ dst, int n)
{
    const int i = blockIdx.x * 256 + threadIdx.x;
    if (i < n) dst[i] = f2bf(src[i]);
}

// ---------------- GEMM1: ht[t][m] = relu(hbias[m] + sum_k Wcomb[m][k]*Gt[t][k]) ----------------
// block = 512 threads = 8 waves (4 m-groups x 2 n-groups). Block tile: M=512, N=128.
__global__ __launch_bounds__(512, 2)
void k_gemm1(const unsigned short* __restrict__ A,   // Wcomb [512][864] bf16
             const unsigned short* __restrict__ B,   // Gt [T][864] bf16
             const float* __restrict__ hbias,
             unsigned short* __restrict__ ht)        // [T][512] bf16
{
    const int lane = threadIdx.x & 63;
    const int w = threadIdx.x >> 6;       // 0..7
    const int wm = w & 3;
    const int wn = w >> 2;
    const int quad = lane >> 4;
    const int l16 = lane & 15;
    const int m0 = wm * 128;
    const int n0 = blockIdx.x * 128 + wn * 64;

    const unsigned short* ab[8];
    const unsigned short* bb[4];
#pragma unroll
    for (int mt = 0; mt < 8; ++mt)
        ab[mt] = A + (size_t)(m0 + mt * 16 + l16) * KTOT + quad * 8;
#pragma unroll
    for (int nt = 0; nt < 4; ++nt)
        bb[nt] = B + (size_t)(n0 + nt * 16 + l16) * KTOT + quad * 8;

    floatx4 acc[8][4];
    const floatx4 vzero = {0.f, 0.f, 0.f, 0.f};
#pragma unroll
    for (int mt = 0; mt < 8; ++mt)
#pragma unroll
        for (int nt = 0; nt < 4; ++nt) acc[mt][nt] = vzero;

    for (int k0 = 0; k0 < KTOT; k0 += 32) {
        short8 bfr[4], afr[8];
#pragma unroll
        for (int nt = 0; nt < 4; ++nt)
            bfr[nt] = *reinterpret_cast<const short8*>(bb[nt] + k0);
#pragma unroll
        for (int mt = 0; mt < 8; ++mt)
            afr[mt] = *reinterpret_cast<const short8*>(ab[mt] + k0);
#pragma unroll
        for (int mt = 0; mt < 8; ++mt)
#pragma unroll
            for (int nt = 0; nt < 4; ++nt)
                acc[mt][nt] = __builtin_amdgcn_mfma_f32_16x16x32_bf16(
                    afr[mt], bfr[nt], acc[mt][nt], 0, 0, 0);
    }

#pragma unroll
    for (int mt = 0; mt < 8; ++mt) {
        const int mb = m0 + mt * 16 + quad * 4;
        const floatx4 hb = *reinterpret_cast<const floatx4*>(hbias + mb);
#pragma unroll
        for (int nt = 0; nt < 4; ++nt) {
            const int t = n0 + nt * 16 + l16;
            ushort4 st;
            float v;
            v = acc[mt][nt][0] + hb[0]; st.x = f2bf(v > 0.f ? v : 0.f);
            v = acc[mt][nt][1] + hb[1]; st.y = f2bf(v > 0.f ? v : 0.f);
            v = acc[mt][nt][2] + hb[2]; st.z = f2bf(v > 0.f ? v : 0.f);
            v = acc[mt][nt][3] + hb[3]; st.w = f2bf(v > 0.f ? v : 0.f);
            *reinterpret_cast<ushort4*>(ht + (size_t)t * SD + mb) = st;
        }
    }
}

// ---------------- GEMM2: out[q][t] = bp2[q] + sum_m Wp2[q][m]*ht[t][m] ----------------
// block = 256 threads = 4 waves, each wave M=64; block tile M=256 (full), N=64.
__global__ __launch_bounds__(256, 2)
void k_gemm2(const unsigned short* __restrict__ A,  // Wp2b [256][512] bf16
             const unsigned short* __restrict__ B,  // ht [T][512] bf16
             const float* __restrict__ bp2,
             float* __restrict__ out)               // [256][T] fp32
{
    const int lane = threadIdx.x & 63;
    const int w = threadIdx.x >> 6;   // 0..3
    const int quad = lane >> 4;
    const int l16 = lane & 15;
    const int m0 = w * 64;
    const int n0 = blockIdx.x * 64;

    const unsigned short* ab[4];
    const unsigned short* bb[4];
#pragma unroll
    for (int mt = 0; mt < 4; ++mt)
        ab[mt] = A + (size_t)(m0 + mt * 16 + l16) * SD + quad * 8;
#pragma unroll
    for (int nt = 0; nt < 4; ++nt)
        bb[nt] = B + (size_t)(n0 + nt * 16 + l16) * SD + quad * 8;

    floatx4 acc[4][4];
    const floatx4 vzero = {0.f, 0.f, 0.f, 0.f};
#pragma unroll
    for (int mt = 0; mt < 4; ++mt)
#pragma unroll
        for (int nt = 0; nt < 4; ++nt) acc[mt][nt] = vzero;

    for (int k0 = 0; k0 < SD; k0 += 32) {
        short8 bfr[4], afr[4];
#pragma unroll
        for (int nt = 0; nt < 4; ++nt)
            bfr[nt] = *reinterpret_cast<const short8*>(bb[nt] + k0);
#pragma unroll
        for (int mt = 0; mt < 4; ++mt)
            afr[mt] = *reinterpret_cast<const short8*>(ab[mt] + k0);
#pragma unroll
        for (int mt = 0; mt < 4; ++mt)
#pragma unroll
            for (int nt = 0; nt < 4; ++nt)
                acc[mt][nt] = __builtin_amdgcn_mfma_f32_16x16x32_bf16(
                    afr[mt], bfr[nt], acc[mt][nt], 0, 0, 0);
    }

#pragma unroll
    for (int mt = 0; mt < 4; ++mt) {
        const int mb = m0 + mt * 16 + quad * 4;
        const floatx4 bz = *reinterpret_cast<const floatx4*>(bp2 + mb);
#pragma unroll
        for (int nt = 0; nt < 4; ++nt) {
            const int t = n0 + nt * 16 + l16;
#pragma unroll
            for (int j = 0; j < 4; ++j)
                out[(size_t)(mb + j) * T_LEN + t] = acc[mt][nt][j] + bz[j];
        }
    }
}

// ---------------- column-wise log_softmax over 256 channels, in place ----------------
__global__ __launch_bounds__(256)
void k_logsoftmax(float* __restrict__ out)
{
    const int t = blockIdx.x * 256 + threadIdx.x;
    float mx = -1e30f;
    for (int q = 0; q < QD; ++q) mx = fmaxf(mx, out[(size_t)q * T_LEN + t]);
    float s = 0.f;
    for (int q = 0; q < QD; ++q) s += __expf(out[(size_t)q * T_LEN + t] - mx);
    const float lse = mx + __logf(s);
    for (int q = 0; q < QD; ++q) out[(size_t)q * T_LEN + t] -= lse;
}

extern "C" void kernel_launch(void* const* d_in, const int* in_sizes, int n_in,
                              void* d_out, int out_size, void* d_ws, size_t ws_size,
                              hipStream_t stream)
{
    (void)in_sizes; (void)n_in; (void)out_size; (void)ws_size;
    const float* x     = (const float*)d_in[0];
    const float* Wc    = (const float*)d_in[1];
    const float* bc    = (const float*)d_in[2];
    const float* Wt    = (const float*)d_in[3];
    const float* bt    = (const float*)d_in[4];
    const float* Ws    = (const float*)d_in[5];
    const float* bs    = (const float*)d_in[6];
    const float* Wskip = (const float*)d_in[7];
    const float* bskip = (const float*)d_in[8];
    const float* Wd    = (const float*)d_in[9];
    const float* bd    = (const float*)d_in[10];
    const float* Wp1   = (const float*)d_in[11];
    const float* bp1   = (const float*)d_in[12];
    const float* Wp2   = (const float*)d_in[13];
    const float* bp2   = (const float*)d_in[14];
    float* out = (float*)d_out;

    char* p = (char*)d_ws;
    float* xa = (float*)p;                      p += (size_t)RD * T_LEN * 4;
    float* xb = (float*)p;                      p += (size_t)RD * T_LEN * 4;
    unsigned short* Gt = (unsigned short*)p;    p += (size_t)T_LEN * KTOT * 2;
    unsigned short* ht = (unsigned short*)p;    p += (size_t)T_LEN * SD * 2;
    unsigned short* Wcomb = (unsigned short*)p; p += (size_t)SD * KTOT * 2;
    unsigned short* Wp2b = (unsigned short*)p;  p += (size_t)QD * SD * 2;
    float* hbias = (float*)p;                   p += (size_t)SD * 4;

    k_wcomb<<<(SD * KTOT + 255) / 256, 256, 0, stream>>>(Wp1, Wskip, Wcomb);
    k_hbias<<<1, 512, 0, stream>>>(Wp1, bp1, bskip, hbias);
    k_cvt<<<(QD * SD + 255) / 256, 256, 0, stream>>>(Wp2, Wp2b, QD * SD);
    k_conv_init<<<T_LEN / 256, 256, 0, stream>>>(x, Wc, bc, xa);

    static const int dil[NL] = {1, 2, 4, 8, 16, 32, 64, 128, 256,
                                1, 2, 4, 8, 16, 32, 64, 128, 256,
                                1, 2, 4, 8, 16, 32, 64, 128, 256};
    const float* cur = xa;
    float* nxt = xb;
    for (int i = 0; i < NL; ++i) {
        k_layer<<<T_LEN / 256, 256, 0, stream>>>(
            cur, nxt, Gt,
            Wt + (size_t)i * RD * RD * 3, bt + (size_t)i * RD,
            Ws + (size_t)i * RD * RD * 3, bs + (size_t)i * RD,
            Wd + (size_t)i * RD * RD,     bd + (size_t)i * RD,
            dil[i], i);
        float* tmp = (float*)cur;
        cur = nxt;
        nxt = tmp;
    }

    k_gemm1<<<T_LEN / 128, 512, 0, stream>>>(Wcomb, Gt, hbias, ht);
    k_gemm2<<<T_LEN / 64, 256, 0, stream>>>(Wp2b, ht, bp2, out);
    k_logsoftmax<<<T_LEN / 256, 256, 0, stream>>>(out);
}

// Round 2
// 1361.114 us; speedup vs baseline: 2.2679x; 2.2679x over previous
//
#include <hip/hip_runtime.h>

#define T_LEN 131072
#define RD 32
#define SD 512
#define QD 256
#define NL 27
#define KTOT (NL * RD)   // 864

typedef __attribute__((ext_vector_type(8))) short short8;
typedef __attribute__((ext_vector_type(4))) float floatx4;

__device__ __forceinline__ unsigned short f2bf(float f) {
    union { float f; unsigned int i; } v; v.f = f;
    unsigned int r = v.i + 0x7fffu + ((v.i >> 16) & 1u);  // RNE
    return (unsigned short)(r >> 16);
}

// ---------------- initial conv: [1,T] -> [T][32] fp32 t-major, k=3, pad=1 ----------------
__global__ __launch_bounds__(256)
void k_conv_init(const float* __restrict__ x, const float* __restrict__ Wc,
                 const float* __restrict__ bc, float* __restrict__ xout)
{
    const int t = blockIdx.x * 256 + threadIdx.x;
    const float xm = (t > 0) ? x[t - 1] : 0.f;
    const float x0 = x[t];
    const float xp = (t < T_LEN - 1) ? x[t + 1] : 0.f;
    float* row = xout + (size_t)t * RD;
#pragma unroll
    for (int o = 0; o < RD; ++o) {
        row[o] = bc[o] + Wc[o * 3 + 0] * xm + Wc[o * 3 + 1] * x0 + Wc[o * 3 + 2] * xp;
    }
}

// ---------------- weight prep: Wg[l][64][96] bf16 (k = j*32+c), Wdb[l][32][32] bf16 ----------------
__global__ __launch_bounds__(256)
void k_wprep(const float* __restrict__ Wt, const float* __restrict__ Ws,
             const float* __restrict__ Wd,
             unsigned short* __restrict__ Wg, unsigned short* __restrict__ Wdb)
{
    const int idx = blockIdx.x * 256 + threadIdx.x;
    const int n1 = NL * 64 * 96;
    const int n2 = NL * RD * RD;
    if (idx < n1) {
        const int l = idx / (64 * 96);
        const int rem = idx % (64 * 96);
        const int m = rem / 96;
        const int k = rem % 96;
        const int j = k / 32;
        const int c = k % 32;
        float v;
        if (m < 32) v = Wt[(((size_t)l * RD + m) * RD + c) * 3 + j];
        else        v = Ws[(((size_t)l * RD + (m - 32)) * RD + c) * 3 + j];
        Wg[idx] = f2bf(v);
    } else if (idx < n1 + n2) {
        const int i2 = idx - n1;
        Wdb[i2] = f2bf(Wd[i2]);
    }
}

// ---------------- one residual layer via MFMA ----------------
// gates: D[64][t] = Wg[64][96] @ Xs[96][t],  Xs[j*32+c][t] = x[t+(j-1)d][c]
// g[o] = tanh(D[o]+bt[o]) * sigmoid(D[32+o]+bs[o]),  o in [0,32)
// xout[t][o] = xin[t][o] + bd[o] + (Wd @ g)[o][t]
__global__ __launch_bounds__(256)
void k_layer_mfma(const float* __restrict__ xin, float* __restrict__ xout,
                  unsigned short* __restrict__ Gt,
                  const unsigned short* __restrict__ Wg,   // [64][96] bf16
                  const unsigned short* __restrict__ Wdb,  // [32][32] bf16
                  const float* __restrict__ bt, const float* __restrict__ bs,
                  const float* __restrict__ bd, int d, int layer)
{
    __shared__ unsigned short gtile[64 * 32];  // [t_local][c] bf16, 4 KB
    const int tid = threadIdx.x;
    const int lane = tid & 63;
    const int w = tid >> 6;        // wave 0..3
    const int quad = lane >> 4;
    const int l16 = lane & 15;
    const int tloc = w * 16 + l16;
    const int t = blockIdx.x * 64 + tloc;

    // A fragments: lane holds A[m=l16][k=quad*8+j] per 16-row tile, per 32-k chunk
    short8 afr[3][4];
#pragma unroll
    for (int j = 0; j < 3; ++j)
#pragma unroll
        for (int mt = 0; mt < 4; ++mt)
            afr[j][mt] = *reinterpret_cast<const short8*>(
                Wg + (size_t)(mt * 16 + l16) * 96 + j * 32 + quad * 8);

    floatx4 acc[4];
    const floatx4 vzero = {0.f, 0.f, 0.f, 0.f};
#pragma unroll
    for (int mt = 0; mt < 4; ++mt) acc[mt] = vzero;

#pragma unroll
    for (int j = 0; j < 3; ++j) {
        const int tt = t + (j - 1) * d;
        short8 b;
        if (tt >= 0 && tt < T_LEN) {
            const floatx4* px = reinterpret_cast<const floatx4*>(xin + (size_t)tt * RD + quad * 8);
            const floatx4 lo = px[0];
            const floatx4 hi = px[1];
            b[0] = (short)f2bf(lo[0]); b[1] = (short)f2bf(lo[1]);
            b[2] = (short)f2bf(lo[2]); b[3] = (short)f2bf(lo[3]);
            b[4] = (short)f2bf(hi[0]); b[5] = (short)f2bf(hi[1]);
            b[6] = (short)f2bf(hi[2]); b[7] = (short)f2bf(hi[3]);
        } else {
            for (int i = 0; i < 8; ++i) b[i] = 0;
        }
#pragma unroll
        for (int mt = 0; mt < 4; ++mt)
            acc[mt] = __builtin_amdgcn_mfma_f32_16x16x32_bf16(afr[j][mt], b, acc[mt], 0, 0, 0);
    }

    // activations: lane holds a_t for channels {pair*16+quad*4+r} (mt=pair) and
    // a_s for the same channels (mt=2+pair), all at its own t
#pragma unroll
    for (int pair = 0; pair < 2; ++pair) {
        const floatx4 bt4 = *reinterpret_cast<const floatx4*>(bt + pair * 16 + quad * 4);
        const floatx4 bs4 = *reinterpret_cast<const floatx4*>(bs + pair * 16 + quad * 4);
        ushort4 u;
        unsigned short us[4];
#pragma unroll
        for (int r = 0; r < 4; ++r) {
            const float a1 = acc[pair][r] + bt4[r];
            const float a2 = acc[2 + pair][r] + bs4[r];
            const float th = 1.f - __fdividef(2.f, __expf(2.f * a1) + 1.f);
            const float sg = __fdividef(1.f, 1.f + __expf(-a2));
            us[r] = f2bf(th * sg);
        }
        u.x = us[0]; u.y = us[1]; u.z = us[2]; u.w = us[3];
        const int cbase = pair * 16 + quad * 4;
        *reinterpret_cast<ushort4*>(&gtile[tloc * 32 + cbase]) = u;
        *reinterpret_cast<ushort4*>(Gt + (size_t)t * KTOT + layer * 32 + cbase) = u;
    }

    __syncthreads();

    // dense residual: D2[32][t] = Wd[32][32] @ g[32][t]
    const short8 bg = *reinterpret_cast<const short8*>(&gtile[tloc * 32 + quad * 8]);
    floatx4 acc2[2];
#pragma unroll
    for (int mt = 0; mt < 2; ++mt) {
        const short8 ad = *reinterpret_cast<const short8*>(
            Wdb + (size_t)(mt * 16 + l16) * 32 + quad * 8);
        acc2[mt] = __builtin_amdgcn_mfma_f32_16x16x32_bf16(ad, bg, vzero, 0, 0, 0);
    }

#pragma unroll
    for (int mt = 0; mt < 2; ++mt) {
        const int m = mt * 16 + quad * 4;
        const floatx4 bd4 = *reinterpret_cast<const floatx4*>(bd + m);
        const floatx4 xi = *reinterpret_cast<const floatx4*>(xin + (size_t)t * RD + m);
        floatx4 o;
#pragma unroll
        for (int r = 0; r < 4; ++r) o[r] = acc2[mt][r] + bd4[r] + xi[r];
        *reinterpret_cast<floatx4*>(xout + (size_t)t * RD + m) = o;
    }
}

// ---------------- Wcomb[m][k] = sum_j Wp1[m][j] * Wskip[l][j][c], k=l*32+c ----------------
__global__ __launch_bounds__(256)
void k_wcomb(const float* __restrict__ Wp1, const float* __restrict__ Wskip,
             unsigned short* __restrict__ Wcomb)
{
    const int idx = blockIdx.x * 256 + threadIdx.x;
    if (idx >= SD * KTOT) return;
    const int m = idx / KTOT;
    const int k = idx % KTOT;
    const int l = k / RD;
    const int c = k % RD;
    const float* wp1r = Wp1 + (size_t)m * SD;
    const float* wsk = Wskip + (size_t)l * SD * RD + c;
    float acc = 0.f;
    for (int j = 0; j < SD; ++j) acc += wp1r[j] * wsk[(size_t)j * RD];
    Wcomb[idx] = f2bf(acc);
}

// ---------------- hbias[m] = bp1[m] + sum_j Wp1[m][j] * (sum_l bskip[l][j]) ----------------
__global__ __launch_bounds__(512)
void k_hbias(const float* __restrict__ Wp1, const float* __restrict__ bp1,
             const float* __restrict__ bskip, float* __restrict__ hbias)
{
    __shared__ float sb[SD];
    const int tid = threadIdx.x;
    float s = 0.f;
    for (int l = 0; l < NL; ++l) s += bskip[l * SD + tid];
    sb[tid] = s;
    __syncthreads();
    float acc = bp1[tid];
    const float* r = Wp1 + (size_t)tid * SD;
    for (int j = 0; j < SD; ++j) acc += r[j] * sb[j];
    hbias[tid] = acc;
}

// ---------------- fp32 -> bf16 cast ----------------
__global__ __launch_bounds__(256)
void k_cvt(const float* __restrict__ src, unsigned short* __restrict__ dst, int n)
{
    const int i = blockIdx.x * 256 + threadIdx.x;
    if (i < n) dst[i] = f2bf(src[i]);
}

// ---------------- GEMM1: ht[t][m] = relu(hbias[m] + sum_k Wcomb[m][k]*Gt[t][k]) ----------------
__global__ __launch_bounds__(512, 2)
void k_gemm1(const unsigned short* __restrict__ A,   // Wcomb [512][864] bf16
             const unsigned short* __restrict__ B,   // Gt [T][864] bf16
             const float* __restrict__ hbias,
             unsigned short* __restrict__ ht)        // [T][512] bf16
{
    const int lane = threadIdx.x & 63;
    const int w = threadIdx.x >> 6;       // 0..7
    const int wm = w & 3;
    const int wn = w >> 2;
    const int quad = lane >> 4;
    const int l16 = lane & 15;
    const int m0 = wm * 128;
    const int n0 = blockIdx.x * 128 + wn * 64;

    const unsigned short* ab[8];
    const unsigned short* bb[4];
#pragma unroll
    for (int mt = 0; mt < 8; ++mt)
        ab[mt] = A + (size_t)(m0 + mt * 16 + l16) * KTOT + quad * 8;
#pragma unroll
    for (int nt = 0; nt < 4; ++nt)
        bb[nt] = B + (size_t)(n0 + nt * 16 + l16) * KTOT + quad * 8;

    floatx4 acc[8][4];
    const floatx4 vzero = {0.f, 0.f, 0.f, 0.f};
#pragma unroll
    for (int mt = 0; mt < 8; ++mt)
#pragma unroll
        for (int nt = 0; nt < 4; ++nt) acc[mt][nt] = vzero;

    for (int k0 = 0; k0 < KTOT; k0 += 32) {
        short8 bfr[4], afr[8];
#pragma unroll
        for (int nt = 0; nt < 4; ++nt)
            bfr[nt] = *reinterpret_cast<const short8*>(bb[nt] + k0);
#pragma unroll
        for (int mt = 0; mt < 8; ++mt)
            afr[mt] = *reinterpret_cast<const short8*>(ab[mt] + k0);
#pragma unroll
        for (int mt = 0; mt < 8; ++mt)
#pragma unroll
            for (int nt = 0; nt < 4; ++nt)
                acc[mt][nt] = __builtin_amdgcn_mfma_f32_16x16x32_bf16(
                    afr[mt], bfr[nt], acc[mt][nt], 0, 0, 0);
    }

#pragma unroll
    for (int mt = 0; mt < 8; ++mt) {
        const int mb = m0 + mt * 16 + quad * 4;
        const floatx4 hb = *reinterpret_cast<const floatx4*>(hbias + mb);
#pragma unroll
        for (int nt = 0; nt < 4; ++nt) {
            const int t = n0 + nt * 16 + l16;
            ushort4 st;
            float v;
            v = acc[mt][nt][0] + hb[0]; st.x = f2bf(v > 0.f ? v : 0.f);
            v = acc[mt][nt][1] + hb[1]; st.y = f2bf(v > 0.f ? v : 0.f);
            v = acc[mt][nt][2] + hb[2]; st.z = f2bf(v > 0.f ? v : 0.f);
            v = acc[mt][nt][3] + hb[3]; st.w = f2bf(v > 0.f ? v : 0.f);
            *reinterpret_cast<ushort4*>(ht + (size_t)t * SD + mb) = st;
        }
    }
}

// ---------------- GEMM2: out[q][t] = bp2[q] + sum_m Wp2[q][m]*ht[t][m] ----------------
__global__ __launch_bounds__(256, 2)
void k_gemm2(const unsigned short* __restrict__ A,  // Wp2b [256][512] bf16
             const unsigned short* __restrict__ B,  // ht [T][512] bf16
             const float* __restrict__ bp2,
             float* __restrict__ out)               // [256][T] fp32
{
    const int lane = threadIdx.x & 63;
    const int w = threadIdx.x >> 6;   // 0..3
    const int quad = lane >> 4;
    const int l16 = lane & 15;
    const int m0 = w * 64;
    const int n0 = blockIdx.x * 64;

    const unsigned short* ab[4];
    const unsigned short* bb[4];
#pragma unroll
    for (int mt = 0; mt < 4; ++mt)
        ab[mt] = A + (size_t)(m0 + mt * 16 + l16) * SD + quad * 8;
#pragma unroll
    for (int nt = 0; nt < 4; ++nt)
        bb[nt] = B + (size_t)(n0 + nt * 16 + l16) * SD + quad * 8;

    floatx4 acc[4][4];
    const floatx4 vzero = {0.f, 0.f, 0.f, 0.f};
#pragma unroll
    for (int mt = 0; mt < 4; ++mt)
#pragma unroll
        for (int nt = 0; nt < 4; ++nt) acc[mt][nt] = vzero;

    for (int k0 = 0; k0 < SD; k0 += 32) {
        short8 bfr[4], afr[4];
#pragma unroll
        for (int nt = 0; nt < 4; ++nt)
            bfr[nt] = *reinterpret_cast<const short8*>(bb[nt] + k0);
#pragma unroll
        for (int mt = 0; mt < 4; ++mt)
            afr[mt] = *reinterpret_cast<const short8*>(ab[mt] + k0);
#pragma unroll
        for (int mt = 0; mt < 4; ++mt)
#pragma unroll
            for (int nt = 0; nt < 4; ++nt)
                acc[mt][nt] = __builtin_amdgcn_mfma_f32_16x16x32_bf16(
                    afr[mt], bfr[nt], acc[mt][nt], 0, 0, 0);
    }

#pragma unroll
    for (int mt = 0; mt < 4; ++mt) {
        const int mb = m0 + mt * 16 + quad * 4;
        const floatx4 bz = *reinterpret_cast<const floatx4*>(bp2 + mb);
#pragma unroll
        for (int nt = 0; nt < 4; ++nt) {
            const int t = n0 + nt * 16 + l16;
#pragma unroll
            for (int j = 0; j < 4; ++j)
                out[(size_t)(mb + j) * T_LEN + t] = acc[mt][nt][j] + bz[j];
        }
    }
}

// ---------------- column-wise log_softmax over 256 channels, in place ----------------
__global__ __launch_bounds__(256)
void k_logsoftmax(float* __restrict__ out)
{
    const int t = blockIdx.x * 256 + threadIdx.x;
    float mx = -1e30f;
    for (int q = 0; q < QD; ++q) mx = fmaxf(mx, out[(size_t)q * T_LEN + t]);
    float s = 0.f;
    for (int q = 0; q < QD; ++q) s += __expf(out[(size_t)q * T_LEN + t] - mx);
    const float lse = mx + __logf(s);
    for (int q = 0; q < QD; ++q) out[(size_t)q * T_LEN + t] -= lse;
}

extern "C" void kernel_launch(void* const* d_in, const int* in_sizes, int n_in,
                              void* d_out, int out_size, void* d_ws, size_t ws_size,
                              hipStream_t stream)
{
    (void)in_sizes; (void)n_in; (void)out_size; (void)ws_size;
    const float* x     = (const float*)d_in[0];
    const float* Wc    = (const float*)d_in[1];
    const float* bc    = (const float*)d_in[2];
    const float* Wt    = (const float*)d_in[3];
    const float* bt    = (const float*)d_in[4];
    const float* Ws    = (const float*)d_in[5];
    const float* bs    = (const float*)d_in[6];
    const float* Wskip = (const float*)d_in[7];
    const float* bskip = (const float*)d_in[8];
    const float* Wd    = (const float*)d_in[9];
    const float* bd    = (const float*)d_in[10];
    const float* Wp1   = (const float*)d_in[11];
    const float* bp1   = (const float*)d_in[12];
    const float* Wp2   = (const float*)d_in[13];
    const float* bp2   = (const float*)d_in[14];
    float* out = (float*)d_out;

    char* p = (char*)d_ws;
    float* xa = (float*)p;                      p += (size_t)T_LEN * RD * 4;
    float* xb = (float*)p;                      p += (size_t)T_LEN * RD * 4;
    unsigned short* Gt = (unsigned short*)p;    p += (size_t)T_LEN * KTOT * 2;
    unsigned short* ht = (unsigned short*)p;    p += (size_t)T_LEN * SD * 2;
    unsigned short* Wcomb = (unsigned short*)p; p += (size_t)SD * KTOT * 2;
    unsigned short* Wp2b = (unsigned short*)p;  p += (size_t)QD * SD * 2;
    unsigned short* Wg = (unsigned short*)p;    p += (size_t)NL * 64 * 96 * 2;
    unsigned short* Wdb = (unsigned short*)p;   p += (size_t)NL * RD * RD * 2;
    float* hbias = (float*)p;                   p += (size_t)SD * 4;

    k_wcomb<<<(SD * KTOT + 255) / 256, 256, 0, stream>>>(Wp1, Wskip, Wcomb);
    k_hbias<<<1, 512, 0, stream>>>(Wp1, bp1, bskip, hbias);
    k_cvt<<<(QD * SD + 255) / 256, 256, 0, stream>>>(Wp2, Wp2b, QD * SD);
    {
        const int nprep = NL * 64 * 96 + NL * RD * RD;
        k_wprep<<<(nprep + 255) / 256, 256, 0, stream>>>(Wt, Ws, Wd, Wg, Wdb);
    }
    k_conv_init<<<T_LEN / 256, 256, 0, stream>>>(x, Wc, bc, xa);

    static const int dil[NL] = {1, 2, 4, 8, 16, 32, 64, 128, 256,
                                1, 2, 4, 8, 16, 32, 64, 128, 256,
                                1, 2, 4, 8, 16, 32, 64, 128, 256};
    const float* cur = xa;
    float* nxt = xb;
    for (int i = 0; i < NL; ++i) {
        k_layer_mfma<<<T_LEN / 64, 256, 0, stream>>>(
            cur, nxt, Gt,
            Wg + (size_t)i * 64 * 96,
            Wdb + (size_t)i * RD * RD,
            bt + (size_t)i * RD,
            bs + (size_t)i * RD,
            bd + (size_t)i * RD,
            dil[i], i);
        float* tmp = (float*)cur;
        cur = nxt;
        nxt = tmp;
    }

    k_gemm1<<<T_LEN / 128, 512, 0, stream>>>(Wcomb, Gt, hbias, ht);
    k_gemm2<<<T_LEN / 64, 256, 0, stream>>>(Wp2b, ht, bp2, out);
    k_logsoftmax<<<T_LEN / 256, 256, 0, stream>>>(out);
}

// Round 3
// 1116.247 us; speedup vs baseline: 2.7653x; 1.2194x over previous
//
#include <hip/hip_runtime.h>

#define T_LEN 131072
#define RD 32
#define SD 512
#define QD 256
#define NL 27
#define KTOT (NL * RD)   // 864

typedef __attribute__((ext_vector_type(8))) short short8;
typedef __attribute__((ext_vector_type(4))) float floatx4;

__device__ __forceinline__ unsigned short f2bf(float f) {
    union { float f; unsigned int i; } v; v.f = f;
    unsigned int r = v.i + 0x7fffu + ((v.i >> 16) & 1u);  // RNE
    return (unsigned short)(r >> 16);
}

__device__ __forceinline__ void gload_lds16(const void* g, void* l) {
    __builtin_amdgcn_global_load_lds(
        (const __attribute__((address_space(1))) unsigned int*)g,
        (__attribute__((address_space(3))) unsigned int*)l, 16, 0, 0);
}

// ---------------- initial conv: [1,T] -> [T][32] fp32 + bf16 copies ----------------
__global__ __launch_bounds__(256)
void k_conv_init(const float* __restrict__ x, const float* __restrict__ Wc,
                 const float* __restrict__ bc, float* __restrict__ xout,
                 unsigned short* __restrict__ xoutb)
{
    const int t = blockIdx.x * 256 + threadIdx.x;
    const float xm = (t > 0) ? x[t - 1] : 0.f;
    const float x0 = x[t];
    const float xp = (t < T_LEN - 1) ? x[t + 1] : 0.f;
    float* row = xout + (size_t)t * RD;
    unsigned short* rowb = xoutb + (size_t)t * RD;
#pragma unroll
    for (int o = 0; o < RD; ++o) {
        const float v = bc[o] + Wc[o * 3 + 0] * xm + Wc[o * 3 + 1] * x0 + Wc[o * 3 + 2] * xp;
        row[o] = v;
        rowb[o] = f2bf(v);
    }
}

// ---------------- weight prep: Wg[l][64][96] bf16 (k = j*32+c), Wdb[l][32][32] bf16 ----------------
__global__ __launch_bounds__(256)
void k_wprep(const float* __restrict__ Wt, const float* __restrict__ Ws,
             const float* __restrict__ Wd,
             unsigned short* __restrict__ Wg, unsigned short* __restrict__ Wdb)
{
    const int idx = blockIdx.x * 256 + threadIdx.x;
    const int n1 = NL * 64 * 96;
    const int n2 = NL * RD * RD;
    if (idx < n1) {
        const int l = idx / (64 * 96);
        const int rem = idx % (64 * 96);
        const int m = rem / 96;
        const int k = rem % 96;
        const int j = k / 32;
        const int c = k % 32;
        float v;
        if (m < 32) v = Wt[(((size_t)l * RD + m) * RD + c) * 3 + j];
        else        v = Ws[(((size_t)l * RD + (m - 32)) * RD + c) * 3 + j];
        Wg[idx] = f2bf(v);
    } else if (idx < n1 + n2) {
        const int i2 = idx - n1;
        Wdb[i2] = f2bf(Wd[i2]);
    }
}

// ---------------- one residual layer via MFMA, 128 t per block ----------------
__global__ __launch_bounds__(256)
void k_layer_mfma(const float* __restrict__ xin, const unsigned short* __restrict__ xinb,
                  float* __restrict__ xout, unsigned short* __restrict__ xoutb,
                  unsigned short* __restrict__ Gt,
                  const unsigned short* __restrict__ Wg,   // [64][96] bf16
                  const unsigned short* __restrict__ Wdb,  // [32][32] bf16
                  const float* __restrict__ bt, const float* __restrict__ bs,
                  const float* __restrict__ bd, int d, int layer)
{
    __shared__ unsigned short gtile[128 * 32];  // [t_local][c] bf16, 8 KB
    const int tid = threadIdx.x;
    const int lane = tid & 63;
    const int w = tid >> 6;        // wave 0..3, t-range w*32..w*32+31
    const int quad = lane >> 4;
    const int l16 = lane & 15;
    const int tbase = blockIdx.x * 128 + w * 32;

    short8 afr[3][4];
#pragma unroll
    for (int j = 0; j < 3; ++j)
#pragma unroll
        for (int mt = 0; mt < 4; ++mt)
            afr[j][mt] = *reinterpret_cast<const short8*>(
                Wg + (size_t)(mt * 16 + l16) * 96 + j * 32 + quad * 8);

    floatx4 acc[4][2];
    const floatx4 vzero = {0.f, 0.f, 0.f, 0.f};
#pragma unroll
    for (int mt = 0; mt < 4; ++mt)
#pragma unroll
        for (int nt = 0; nt < 2; ++nt) acc[mt][nt] = vzero;

#pragma unroll
    for (int nt = 0; nt < 2; ++nt) {
        const int t = tbase + nt * 16 + l16;
#pragma unroll
        for (int j = 0; j < 3; ++j) {
            const int tt = t + (j - 1) * d;
            short8 b;
            if (tt >= 0 && tt < T_LEN) {
                b = *reinterpret_cast<const short8*>(xinb + (size_t)tt * RD + quad * 8);
            } else {
#pragma unroll
                for (int i = 0; i < 8; ++i) b[i] = 0;
            }
#pragma unroll
            for (int mt = 0; mt < 4; ++mt)
                acc[mt][nt] = __builtin_amdgcn_mfma_f32_16x16x32_bf16(afr[j][mt], b, acc[mt][nt], 0, 0, 0);
        }
    }

    // activations
#pragma unroll
    for (int nt = 0; nt < 2; ++nt) {
        const int t = tbase + nt * 16 + l16;
        const int tloc = w * 32 + nt * 16 + l16;
#pragma unroll
        for (int pair = 0; pair < 2; ++pair) {
            const floatx4 bt4 = *reinterpret_cast<const floatx4*>(bt + pair * 16 + quad * 4);
            const floatx4 bs4 = *reinterpret_cast<const floatx4*>(bs + pair * 16 + quad * 4);
            ushort4 u;
            unsigned short us[4];
#pragma unroll
            for (int r = 0; r < 4; ++r) {
                const float a1 = acc[pair][nt][r] + bt4[r];
                const float a2 = acc[2 + pair][nt][r] + bs4[r];
                const float th = 1.f - __fdividef(2.f, __expf(2.f * a1) + 1.f);
                const float sg = __fdividef(1.f, 1.f + __expf(-a2));
                us[r] = f2bf(th * sg);
            }
            u.x = us[0]; u.y = us[1]; u.z = us[2]; u.w = us[3];
            const int cbase = pair * 16 + quad * 4;
            *reinterpret_cast<ushort4*>(&gtile[tloc * 32 + cbase]) = u;
            *reinterpret_cast<ushort4*>(Gt + (size_t)t * KTOT + layer * 32 + cbase) = u;
        }
    }

    __syncthreads();

    // dense residual
    short8 ad[2];
#pragma unroll
    for (int mt = 0; mt < 2; ++mt)
        ad[mt] = *reinterpret_cast<const short8*>(Wdb + (size_t)(mt * 16 + l16) * 32 + quad * 8);

#pragma unroll
    for (int nt = 0; nt < 2; ++nt) {
        const int t = tbase + nt * 16 + l16;
        const int tloc = w * 32 + nt * 16 + l16;
        const short8 bg = *reinterpret_cast<const short8*>(&gtile[tloc * 32 + quad * 8]);
#pragma unroll
        for (int mt = 0; mt < 2; ++mt) {
            const floatx4 a2 = __builtin_amdgcn_mfma_f32_16x16x32_bf16(ad[mt], bg, vzero, 0, 0, 0);
            const int m = mt * 16 + quad * 4;
            const floatx4 bd4 = *reinterpret_cast<const floatx4*>(bd + m);
            const floatx4 xi = *reinterpret_cast<const floatx4*>(xin + (size_t)t * RD + m);
            floatx4 o;
            ushort4 ob;
            o[0] = a2[0] + bd4[0] + xi[0]; ob.x = f2bf(o[0]);
            o[1] = a2[1] + bd4[1] + xi[1]; ob.y = f2bf(o[1]);
            o[2] = a2[2] + bd4[2] + xi[2]; ob.z = f2bf(o[2]);
            o[3] = a2[3] + bd4[3] + xi[3]; ob.w = f2bf(o[3]);
            *reinterpret_cast<floatx4*>(xout + (size_t)t * RD + m) = o;
            *reinterpret_cast<ushort4*>(xoutb + (size_t)t * RD + m) = ob;
        }
    }
}

// ---------------- Wcomb[m][k] = sum_j Wp1[m][j] * Wskip[l][j][c], k=l*32+c ----------------
__global__ __launch_bounds__(256)
void k_wcomb(const float* __restrict__ Wp1, const float* __restrict__ Wskip,
             unsigned short* __restrict__ Wcomb)
{
    const int idx = blockIdx.x * 256 + threadIdx.x;
    if (idx >= SD * KTOT) return;
    const int m = idx / KTOT;
    const int k = idx % KTOT;
    const int l = k / RD;
    const int c = k % RD;
    const float* wp1r = Wp1 + (size_t)m * SD;
    const float* wsk = Wskip + (size_t)l * SD * RD + c;
    float acc = 0.f;
    for (int j = 0; j < SD; ++j) acc += wp1r[j] * wsk[(size_t)j * RD];
    Wcomb[idx] = f2bf(acc);
}

// ---------------- hbias[m] = bp1[m] + sum_j Wp1[m][j] * (sum_l bskip[l][j]) ----------------
__global__ __launch_bounds__(512)
void k_hbias(const float* __restrict__ Wp1, const float* __restrict__ bp1,
             const float* __restrict__ bskip, float* __restrict__ hbias)
{
    __shared__ float sb[SD];
    const int tid = threadIdx.x;
    float s = 0.f;
    for (int l = 0; l < NL; ++l) s += bskip[l * SD + tid];
    sb[tid] = s;
    __syncthreads();
    float acc = bp1[tid];
    const float* r = Wp1 + (size_t)tid * SD;
    for (int j = 0; j < SD; ++j) acc += r[j] * sb[j];
    hbias[tid] = acc;
}

// ---------------- fp32 -> bf16 cast ----------------
__global__ __launch_bounds__(256)
void k_cvt(const float* __restrict__ src, unsigned short* __restrict__ dst, int n)
{
    const int i = blockIdx.x * 256 + threadIdx.x;
    if (i < n) dst[i] = f2bf(src[i]);
}

// ---------------- GEMM1 (m97-style): ht[t][m] = relu(hbias[m] + Wcomb@Gt) ----------------
// grid: (bid&3)=m-block of 128, (bid>>2)=n-block of 128. 256 threads, 4 waves 2x2.
__global__ __launch_bounds__(256)
void k_gemm1(const unsigned short* __restrict__ A,   // Wcomb [512][864] bf16
             const unsigned short* __restrict__ B,   // Gt [T][864] bf16
             const float* __restrict__ hbias,
             unsigned short* __restrict__ ht)        // [T][512] bf16
{
    __shared__ unsigned short ldsA[128 * 32];  // 8 KB
    __shared__ unsigned short ldsB[128 * 32];  // 8 KB
    const int tid = threadIdx.x;
    const int lane = tid & 63;
    const int w = tid >> 6;
    const int wm = w & 1;
    const int wn = w >> 1;
    const int quad = lane >> 4;
    const int l16 = lane & 15;
    const int m0 = (blockIdx.x & 3) * 128;
    const int n0 = (blockIdx.x >> 2) * 128;

    const int r4 = lane >> 2;     // 0..15 row within staging call
    const int c4 = lane & 3;      // 16B slot within 64B row-chunk

    floatx4 acc[4][4];
    const floatx4 vzero = {0.f, 0.f, 0.f, 0.f};
#pragma unroll
    for (int mt = 0; mt < 4; ++mt)
#pragma unroll
        for (int nt = 0; nt < 4; ++nt) acc[mt][nt] = vzero;

    for (int kc = 0; kc < KTOT / 32; ++kc) {
        const int k0 = kc * 32;
        // stage A and B chunks: each wave loads 32 rows of each (2 calls x 16 rows)
#pragma unroll
        for (int c = 0; c < 2; ++c) {
            const int row = w * 32 + c * 16;
            gload_lds16(A + (size_t)(m0 + row + r4) * KTOT + k0 + c4 * 8,
                        &ldsA[(size_t)row * 32]);
            gload_lds16(B + (size_t)(n0 + row + r4) * KTOT + k0 + c4 * 8,
                        &ldsB[(size_t)row * 32]);
        }
        __syncthreads();

        short8 afr[4], bfr[4];
#pragma unroll
        for (int mt = 0; mt < 4; ++mt)
            afr[mt] = *reinterpret_cast<const short8*>(&ldsA[(wm * 64 + mt * 16 + l16) * 32 + quad * 8]);
#pragma unroll
        for (int nt = 0; nt < 4; ++nt)
            bfr[nt] = *reinterpret_cast<const short8*>(&ldsB[(wn * 64 + nt * 16 + l16) * 32 + quad * 8]);
#pragma unroll
        for (int mt = 0; mt < 4; ++mt)
#pragma unroll
            for (int nt = 0; nt < 4; ++nt)
                acc[mt][nt] = __builtin_amdgcn_mfma_f32_16x16x32_bf16(afr[mt], bfr[nt], acc[mt][nt], 0, 0, 0);
        __syncthreads();
    }

#pragma unroll
    for (int mt = 0; mt < 4; ++mt) {
        const int m = m0 + wm * 64 + mt * 16 + quad * 4;
        const floatx4 hb = *reinterpret_cast<const floatx4*>(hbias + m);
#pragma unroll
        for (int nt = 0; nt < 4; ++nt) {
            const int t = n0 + wn * 64 + nt * 16 + l16;
            ushort4 st;
            float v;
            v = acc[mt][nt][0] + hb[0]; st.x = f2bf(v > 0.f ? v : 0.f);
            v = acc[mt][nt][1] + hb[1]; st.y = f2bf(v > 0.f ? v : 0.f);
            v = acc[mt][nt][2] + hb[2]; st.z = f2bf(v > 0.f ? v : 0.f);
            v = acc[mt][nt][3] + hb[3]; st.w = f2bf(v > 0.f ? v : 0.f);
            *reinterpret_cast<ushort4*>(ht + (size_t)t * SD + m) = st;
        }
    }
}

// ---------------- GEMM2 + fused log_softmax ----------------
// out[q][t] = (bp2[q] + sum_m Wp2[q][m]*ht[t][m]) - lse[t]
__global__ __launch_bounds__(256)
void k_gemm2_lsm(const unsigned short* __restrict__ A,  // Wp2b [256][512] bf16
                 const unsigned short* __restrict__ B,  // ht [T][512] bf16
                 const float* __restrict__ bp2,
                 float* __restrict__ out)               // [256][T] fp32
{
    __shared__ float redmax[4 * 16 * 16];  // [nt][l16][w*4+quad]
    __shared__ float redsum[4 * 16 * 16];
    const int tid = threadIdx.x;
    const int lane = tid & 63;
    const int w = tid >> 6;   // 0..3
    const int quad = lane >> 4;
    const int l16 = lane & 15;
    const int m0 = w * 64;
    const int n0 = blockIdx.x * 64;

    const unsigned short* ab[4];
    const unsigned short* bb[4];
#pragma unroll
    for (int mt = 0; mt < 4; ++mt)
        ab[mt] = A + (size_t)(m0 + mt * 16 + l16) * SD + quad * 8;
#pragma unroll
    for (int nt = 0; nt < 4; ++nt)
        bb[nt] = B + (size_t)(n0 + nt * 16 + l16) * SD + quad * 8;

    floatx4 acc[4][4];
    const floatx4 vzero = {0.f, 0.f, 0.f, 0.f};
#pragma unroll
    for (int mt = 0; mt < 4; ++mt)
#pragma unroll
        for (int nt = 0; nt < 4; ++nt) acc[mt][nt] = vzero;

    for (int k0 = 0; k0 < SD; k0 += 32) {
        short8 bfr[4], afr[4];
#pragma unroll
        for (int nt = 0; nt < 4; ++nt)
            bfr[nt] = *reinterpret_cast<const short8*>(bb[nt] + k0);
#pragma unroll
        for (int mt = 0; mt < 4; ++mt)
            afr[mt] = *reinterpret_cast<const short8*>(ab[mt] + k0);
#pragma unroll
        for (int mt = 0; mt < 4; ++mt)
#pragma unroll
            for (int nt = 0; nt < 4; ++nt)
                acc[mt][nt] = __builtin_amdgcn_mfma_f32_16x16x32_bf16(
                    afr[mt], bfr[nt], acc[mt][nt], 0, 0, 0);
    }

    // add bias
#pragma unroll
    for (int mt = 0; mt < 4; ++mt) {
        const int mb = m0 + mt * 16 + quad * 4;
        const floatx4 bz = *reinterpret_cast<const floatx4*>(bp2 + mb);
#pragma unroll
        for (int nt = 0; nt < 4; ++nt)
#pragma unroll
            for (int j = 0; j < 4; ++j) acc[mt][nt][j] += bz[j];
    }

    // pass 1: local max per (lane, nt) over its 16 q-values
#pragma unroll
    for (int nt = 0; nt < 4; ++nt) {
        float lm = -1e30f;
#pragma unroll
        for (int mt = 0; mt < 4; ++mt)
#pragma unroll
            for (int j = 0; j < 4; ++j) lm = fmaxf(lm, acc[mt][nt][j]);
        redmax[nt * 256 + l16 * 16 + w * 4 + quad] = lm;
    }
    __syncthreads();

    float lse[4];
#pragma unroll
    for (int nt = 0; nt < 4; ++nt) {
        float gm = -1e30f;
#pragma unroll
        for (int i = 0; i < 16; ++i) gm = fmaxf(gm, redmax[nt * 256 + l16 * 16 + i]);
        float ls = 0.f;
#pragma unroll
        for (int mt = 0; mt < 4; ++mt)
#pragma unroll
            for (int j = 0; j < 4; ++j) ls += __expf(acc[mt][nt][j] - gm);
        redsum[nt * 256 + l16 * 16 + w * 4 + quad] = ls;
        lse[nt] = gm;   // stash gmax
    }
    __syncthreads();

#pragma unroll
    for (int nt = 0; nt < 4; ++nt) {
        float tot = 0.f;
#pragma unroll
        for (int i = 0; i < 16; ++i) tot += redsum[nt * 256 + l16 * 16 + i];
        lse[nt] = lse[nt] + __logf(tot);
    }

#pragma unroll
    for (int mt = 0; mt < 4; ++mt) {
        const int mb = m0 + mt * 16 + quad * 4;
#pragma unroll
        for (int nt = 0; nt < 4; ++nt) {
            const int t = n0 + nt * 16 + l16;
#pragma unroll
            for (int j = 0; j < 4; ++j)
                out[(size_t)(mb + j) * T_LEN + t] = acc[mt][nt][j] - lse[nt];
        }
    }
}

extern "C" void kernel_launch(void* const* d_in, const int* in_sizes, int n_in,
                              void* d_out, int out_size, void* d_ws, size_t ws_size,
                              hipStream_t stream)
{
    (void)in_sizes; (void)n_in; (void)out_size; (void)ws_size;
    const float* x     = (const float*)d_in[0];
    const float* Wc    = (const float*)d_in[1];
    const float* bc    = (const float*)d_in[2];
    const float* Wt    = (const float*)d_in[3];
    const float* bt    = (const float*)d_in[4];
    const float* Ws    = (const float*)d_in[5];
    const float* bs    = (const float*)d_in[6];
    const float* Wskip = (const float*)d_in[7];
    const float* bskip = (const float*)d_in[8];
    const float* Wd    = (const float*)d_in[9];
    const float* bd    = (const float*)d_in[10];
    const float* Wp1   = (const float*)d_in[11];
    const float* bp1   = (const float*)d_in[12];
    const float* Wp2   = (const float*)d_in[13];
    const float* bp2   = (const float*)d_in[14];
    float* out = (float*)d_out;

    char* p = (char*)d_ws;
    unsigned short* Gt = (unsigned short*)p;    p += (size_t)T_LEN * KTOT * 2;   // 226.5 MB
    unsigned short* ht = (unsigned short*)p;    p += (size_t)T_LEN * SD * 2;     // 134 MB
    unsigned short* Wcomb = (unsigned short*)p; p += (size_t)SD * KTOT * 2;
    unsigned short* Wp2b = (unsigned short*)p;  p += (size_t)QD * SD * 2;
    unsigned short* Wg = (unsigned short*)p;    p += (size_t)NL * 64 * 96 * 2;
    unsigned short* Wdb = (unsigned short*)p;   p += (size_t)NL * RD * RD * 2;
    float* hbias = (float*)p;                   p += (size_t)SD * 4;

    // x buffers alias the ht region (dead before gemm1 writes ht)
    char* q = (char*)ht;
    float* xa = (float*)q;                      q += (size_t)T_LEN * RD * 4;
    float* xb = (float*)q;                      q += (size_t)T_LEN * RD * 4;
    unsigned short* xba = (unsigned short*)q;   q += (size_t)T_LEN * RD * 2;
    unsigned short* xbb = (unsigned short*)q;   q += (size_t)T_LEN * RD * 2;

    k_wcomb<<<(SD * KTOT + 255) / 256, 256, 0, stream>>>(Wp1, Wskip, Wcomb);
    k_hbias<<<1, 512, 0, stream>>>(Wp1, bp1, bskip, hbias);
    k_cvt<<<(QD * SD + 255) / 256, 256, 0, stream>>>(Wp2, Wp2b, QD * SD);
    {
        const int nprep = NL * 64 * 96 + NL * RD * RD;
        k_wprep<<<(nprep + 255) / 256, 256, 0, stream>>>(Wt, Ws, Wd, Wg, Wdb);
    }
    k_conv_init<<<T_LEN / 256, 256, 0, stream>>>(x, Wc, bc, xa, xba);

    static const int dil[NL] = {1, 2, 4, 8, 16, 32, 64, 128, 256,
                                1, 2, 4, 8, 16, 32, 64, 128, 256,
                                1, 2, 4, 8, 16, 32, 64, 128, 256};
    const float* cur = xa;
    const unsigned short* curb = xba;
    float* nxt = xb;
    unsigned short* nxtb = xbb;
    for (int i = 0; i < NL; ++i) {
        k_layer_mfma<<<T_LEN / 128, 256, 0, stream>>>(
            cur, curb, nxt, nxtb, Gt,
            Wg + (size_t)i * 64 * 96,
            Wdb + (size_t)i * RD * RD,
            bt + (size_t)i * RD,
            bs + (size_t)i * RD,
            bd + (size_t)i * RD,
            dil[i], i);
        float* tf = (float*)cur; cur = nxt; nxt = tf;
        unsigned short* tb = (unsigned short*)curb; curb = nxtb; nxtb = tb;
    }

    k_gemm1<<<4 * (T_LEN / 128), 256, 0, stream>>>(Wcomb, Gt, hbias, ht);
    k_gemm2_lsm<<<T_LEN / 64, 256, 0, stream>>>(Wp2b, ht, bp2, out);
}

// Round 4
// 1105.833 us; speedup vs baseline: 2.7914x; 1.0094x over previous
//
#include <hip/hip_runtime.h>

#define T_LEN 131072
#define RD 32
#define SD 512
#define QD 256
#define NL 27
#define KTOT (NL * RD)   // 864

typedef __attribute__((ext_vector_type(8))) short short8;
typedef __attribute__((ext_vector_type(4))) float floatx4;

__device__ __forceinline__ unsigned short f2bf(float f) {
    union { float f; unsigned int i; } v; v.f = f;
    unsigned int r = v.i + 0x7fffu + ((v.i >> 16) & 1u);  // RNE
    return (unsigned short)(r >> 16);
}

__device__ __forceinline__ void gload_lds16(const void* g, void* l) {
    __builtin_amdgcn_global_load_lds(
        (const __attribute__((address_space(1))) unsigned int*)g,
        (__attribute__((address_space(3))) unsigned int*)l, 16, 0, 0);
}

// ---------------- initial conv: [1,T] -> [T][32] fp32 + bf16 copies ----------------
__global__ __launch_bounds__(256)
void k_conv_init(const float* __restrict__ x, const float* __restrict__ Wc,
                 const float* __restrict__ bc, float* __restrict__ xout,
                 unsigned short* __restrict__ xoutb)
{
    const int t = blockIdx.x * 256 + threadIdx.x;
    const float xm = (t > 0) ? x[t - 1] : 0.f;
    const float x0 = x[t];
    const float xp = (t < T_LEN - 1) ? x[t + 1] : 0.f;
    float* row = xout + (size_t)t * RD;
    unsigned short* rowb = xoutb + (size_t)t * RD;
#pragma unroll
    for (int o = 0; o < RD; ++o) {
        const float v = bc[o] + Wc[o * 3 + 0] * xm + Wc[o * 3 + 1] * x0 + Wc[o * 3 + 2] * xp;
        row[o] = v;
        rowb[o] = f2bf(v);
    }
}

// ---------------- weight prep ----------------
__global__ __launch_bounds__(256)
void k_wprep(const float* __restrict__ Wt, const float* __restrict__ Ws,
             const float* __restrict__ Wd,
             unsigned short* __restrict__ Wg, unsigned short* __restrict__ Wdb)
{
    const int idx = blockIdx.x * 256 + threadIdx.x;
    const int n1 = NL * 64 * 96;
    const int n2 = NL * RD * RD;
    if (idx < n1) {
        const int l = idx / (64 * 96);
        const int rem = idx % (64 * 96);
        const int m = rem / 96;
        const int k = rem % 96;
        const int j = k / 32;
        const int c = k % 32;
        float v;
        if (m < 32) v = Wt[(((size_t)l * RD + m) * RD + c) * 3 + j];
        else        v = Ws[(((size_t)l * RD + (m - 32)) * RD + c) * 3 + j];
        Wg[idx] = f2bf(v);
    } else if (idx < n1 + n2) {
        const int i2 = idx - n1;
        Wdb[i2] = f2bf(Wd[i2]);
    }
}

// ---------------- one residual layer via MFMA, 128 t per block ----------------
__global__ __launch_bounds__(256)
void k_layer_mfma(const float* __restrict__ xin, const unsigned short* __restrict__ xinb,
                  float* __restrict__ xout, unsigned short* __restrict__ xoutb,
                  unsigned short* __restrict__ Gt,
                  const unsigned short* __restrict__ Wg,   // [64][96] bf16
                  const unsigned short* __restrict__ Wdb,  // [32][32] bf16
                  const float* __restrict__ bt, const float* __restrict__ bs,
                  const float* __restrict__ bd, int d, int layer)
{
    __shared__ unsigned short gtile[128 * 32];  // 8 KB
    const int tid = threadIdx.x;
    const int lane = tid & 63;
    const int w = tid >> 6;
    const int quad = lane >> 4;
    const int l16 = lane & 15;
    const int tbase = blockIdx.x * 128 + w * 32;

    short8 afr[3][4];
#pragma unroll
    for (int j = 0; j < 3; ++j)
#pragma unroll
        for (int mt = 0; mt < 4; ++mt)
            afr[j][mt] = *reinterpret_cast<const short8*>(
                Wg + (size_t)(mt * 16 + l16) * 96 + j * 32 + quad * 8);

    floatx4 acc[4][2];
    const floatx4 vzero = {0.f, 0.f, 0.f, 0.f};
#pragma unroll
    for (int mt = 0; mt < 4; ++mt)
#pragma unroll
        for (int nt = 0; nt < 2; ++nt) acc[mt][nt] = vzero;

#pragma unroll
    for (int nt = 0; nt < 2; ++nt) {
        const int t = tbase + nt * 16 + l16;
#pragma unroll
        for (int j = 0; j < 3; ++j) {
            const int tt = t + (j - 1) * d;
            short8 b;
            if (tt >= 0 && tt < T_LEN) {
                b = *reinterpret_cast<const short8*>(xinb + (size_t)tt * RD + quad * 8);
            } else {
#pragma unroll
                for (int i = 0; i < 8; ++i) b[i] = 0;
            }
#pragma unroll
            for (int mt = 0; mt < 4; ++mt)
                acc[mt][nt] = __builtin_amdgcn_mfma_f32_16x16x32_bf16(afr[j][mt], b, acc[mt][nt], 0, 0, 0);
        }
    }

#pragma unroll
    for (int nt = 0; nt < 2; ++nt) {
        const int t = tbase + nt * 16 + l16;
        const int tloc = w * 32 + nt * 16 + l16;
#pragma unroll
        for (int pair = 0; pair < 2; ++pair) {
            const floatx4 bt4 = *reinterpret_cast<const floatx4*>(bt + pair * 16 + quad * 4);
            const floatx4 bs4 = *reinterpret_cast<const floatx4*>(bs + pair * 16 + quad * 4);
            ushort4 u;
            unsigned short us[4];
#pragma unroll
            for (int r = 0; r < 4; ++r) {
                const float a1 = acc[pair][nt][r] + bt4[r];
                const float a2 = acc[2 + pair][nt][r] + bs4[r];
                const float th = 1.f - __fdividef(2.f, __expf(2.f * a1) + 1.f);
                const float sg = __fdividef(1.f, 1.f + __expf(-a2));
                us[r] = f2bf(th * sg);
            }
            u.x = us[0]; u.y = us[1]; u.z = us[2]; u.w = us[3];
            const int cbase = pair * 16 + quad * 4;
            *reinterpret_cast<ushort4*>(&gtile[tloc * 32 + cbase]) = u;
            *reinterpret_cast<ushort4*>(Gt + (size_t)t * KTOT + layer * 32 + cbase) = u;
        }
    }

    __syncthreads();

    short8 ad[2];
#pragma unroll
    for (int mt = 0; mt < 2; ++mt)
        ad[mt] = *reinterpret_cast<const short8*>(Wdb + (size_t)(mt * 16 + l16) * 32 + quad * 8);

#pragma unroll
    for (int nt = 0; nt < 2; ++nt) {
        const int t = tbase + nt * 16 + l16;
        const int tloc = w * 32 + nt * 16 + l16;
        const short8 bg = *reinterpret_cast<const short8*>(&gtile[tloc * 32 + quad * 8]);
#pragma unroll
        for (int mt = 0; mt < 2; ++mt) {
            const floatx4 a2 = __builtin_amdgcn_mfma_f32_16x16x32_bf16(ad[mt], bg, vzero, 0, 0, 0);
            const int m = mt * 16 + quad * 4;
            const floatx4 bd4 = *reinterpret_cast<const floatx4*>(bd + m);
            const floatx4 xi = *reinterpret_cast<const floatx4*>(xin + (size_t)t * RD + m);
            floatx4 o;
            ushort4 ob;
            o[0] = a2[0] + bd4[0] + xi[0]; ob.x = f2bf(o[0]);
            o[1] = a2[1] + bd4[1] + xi[1]; ob.y = f2bf(o[1]);
            o[2] = a2[2] + bd4[2] + xi[2]; ob.z = f2bf(o[2]);
            o[3] = a2[3] + bd4[3] + xi[3]; ob.w = f2bf(o[3]);
            *reinterpret_cast<floatx4*>(xout + (size_t)t * RD + m) = o;
            *reinterpret_cast<ushort4*>(xoutb + (size_t)t * RD + m) = ob;
        }
    }
}

// ---------------- Wcomb ----------------
__global__ __launch_bounds__(256)
void k_wcomb(const float* __restrict__ Wp1, const float* __restrict__ Wskip,
             unsigned short* __restrict__ Wcomb)
{
    const int idx = blockIdx.x * 256 + threadIdx.x;
    if (idx >= SD * KTOT) return;
    const int m = idx / KTOT;
    const int k = idx % KTOT;
    const int l = k / RD;
    const int c = k % RD;
    const float* wp1r = Wp1 + (size_t)m * SD;
    const float* wsk = Wskip + (size_t)l * SD * RD + c;
    float acc = 0.f;
    for (int j = 0; j < SD; ++j) acc += wp1r[j] * wsk[(size_t)j * RD];
    Wcomb[idx] = f2bf(acc);
}

// ---------------- hbias ----------------
__global__ __launch_bounds__(512)
void k_hbias(const float* __restrict__ Wp1, const float* __restrict__ bp1,
             const float* __restrict__ bskip, float* __restrict__ hbias)
{
    __shared__ float sb[SD];
    const int tid = threadIdx.x;
    float s = 0.f;
    for (int l = 0; l < NL; ++l) s += bskip[l * SD + tid];
    sb[tid] = s;
    __syncthreads();
    float acc = bp1[tid];
    const float* r = Wp1 + (size_t)tid * SD;
    for (int j = 0; j < SD; ++j) acc += r[j] * sb[j];
    hbias[tid] = acc;
}

// ---------------- fp32 -> bf16 cast ----------------
__global__ __launch_bounds__(256)
void k_cvt(const float* __restrict__ src, unsigned short* __restrict__ dst, int n)
{
    const int i = blockIdx.x * 256 + threadIdx.x;
    if (i < n) dst[i] = f2bf(src[i]);
}

// ---------------- GEMM1: ht[t][m] = relu(hbias[m] + Wcomb@Gt) ----------------
// XCD-sibling swizzle: m_idx=(g>>3)&3, n_idx=(g&7)+8*(g>>5) -> the 4 m-siblings
// of one n-tile are consecutive in one XCD's dispatch sequence (B reused in L2).
// LDS holds B only (8 KB); A (Wcomb, 864 KB, grid-hot) is read direct from L2.
// Bank-conflict-free via chunk permutation: slot (r,c) holds global chunk
// c ^ ((r>>1)&3); reader uses slot q ^ ((row>>1)&3).
__global__ __launch_bounds__(256)
void k_gemm1(const unsigned short* __restrict__ A,   // Wcomb [512][864] bf16
             const unsigned short* __restrict__ B,   // Gt [T][864] bf16
             const float* __restrict__ hbias,
             unsigned short* __restrict__ ht)        // [T][512] bf16
{
    __shared__ unsigned short ldsB[128 * 32];  // 8 KB
    const int tid = threadIdx.x;
    const int lane = tid & 63;
    const int w = tid >> 6;
    const int wm = w & 1;
    const int wn = w >> 1;
    const int quad = lane >> 4;
    const int l16 = lane & 15;

    const int g = blockIdx.x;
    const int m0 = ((g >> 3) & 3) * 128;
    const int n0 = ((g & 7) + 8 * (g >> 5)) * 128;

    const int r4 = lane >> 2;     // 0..15
    const int c4 = lane & 3;      // LDS 16B slot
    const int srcc = c4 ^ ((r4 >> 1) & 3);   // permuted global chunk
    const int swz = (l16 >> 1) & 3;          // reader-side key

    floatx4 acc[4][4];
    const floatx4 vzero = {0.f, 0.f, 0.f, 0.f};
#pragma unroll
    for (int mt = 0; mt < 4; ++mt)
#pragma unroll
        for (int nt = 0; nt < 4; ++nt) acc[mt][nt] = vzero;

    const unsigned short* arow[4];
#pragma unroll
    for (int mt = 0; mt < 4; ++mt)
        arow[mt] = A + (size_t)(m0 + wm * 64 + mt * 16 + l16) * KTOT + quad * 8;

    for (int kc = 0; kc < KTOT / 32; ++kc) {
        const int k0 = kc * 32;
#pragma unroll
        for (int c = 0; c < 2; ++c) {
            const int row = w * 32 + c * 16;
            gload_lds16(B + (size_t)(n0 + row + r4) * KTOT + k0 + srcc * 8,
                        &ldsB[(size_t)row * 32]);
        }
        short8 afr[4];
#pragma unroll
        for (int mt = 0; mt < 4; ++mt)
            afr[mt] = *reinterpret_cast<const short8*>(arow[mt] + k0);
        __syncthreads();

        short8 bfr[4];
#pragma unroll
        for (int nt = 0; nt < 4; ++nt)
            bfr[nt] = *reinterpret_cast<const short8*>(
                &ldsB[(wn * 64 + nt * 16 + l16) * 32 + (quad ^ swz) * 8]);
#pragma unroll
        for (int mt = 0; mt < 4; ++mt)
#pragma unroll
            for (int nt = 0; nt < 4; ++nt)
                acc[mt][nt] = __builtin_amdgcn_mfma_f32_16x16x32_bf16(afr[mt], bfr[nt], acc[mt][nt], 0, 0, 0);
        __syncthreads();
    }

#pragma unroll
    for (int mt = 0; mt < 4; ++mt) {
        const int m = m0 + wm * 64 + mt * 16 + quad * 4;
        const floatx4 hb = *reinterpret_cast<const floatx4*>(hbias + m);
#pragma unroll
        for (int nt = 0; nt < 4; ++nt) {
            const int t = n0 + wn * 64 + nt * 16 + l16;
            ushort4 st;
            float v;
            v = acc[mt][nt][0] + hb[0]; st.x = f2bf(v > 0.f ? v : 0.f);
            v = acc[mt][nt][1] + hb[1]; st.y = f2bf(v > 0.f ? v : 0.f);
            v = acc[mt][nt][2] + hb[2]; st.z = f2bf(v > 0.f ? v : 0.f);
            v = acc[mt][nt][3] + hb[3]; st.w = f2bf(v > 0.f ? v : 0.f);
            *reinterpret_cast<ushort4*>(ht + (size_t)t * SD + m) = st;
        }
    }
}

// ---------------- GEMM2 + fused log_softmax, LDS-staged B ----------------
__global__ __launch_bounds__(256)
void k_gemm2_lsm(const unsigned short* __restrict__ A,  // Wp2b [256][512] bf16
                 const unsigned short* __restrict__ B,  // ht [T][512] bf16
                 const float* __restrict__ bp2,
                 float* __restrict__ out)               // [256][T] fp32
{
    __shared__ unsigned short ldsB[64 * 32];  // 4 KB
    __shared__ float redmax[4 * 16 * 16];
    __shared__ float redsum[4 * 16 * 16];
    const int tid = threadIdx.x;
    const int lane = tid & 63;
    const int w = tid >> 6;   // 0..3 = m-slice
    const int quad = lane >> 4;
    const int l16 = lane & 15;
    const int m0 = w * 64;
    const int n0 = blockIdx.x * 64;

    const int r4 = lane >> 2;
    const int c4 = lane & 3;
    const int srcc = c4 ^ ((r4 >> 1) & 3);
    const int swz = (l16 >> 1) & 3;

    const unsigned short* ab[4];
#pragma unroll
    for (int mt = 0; mt < 4; ++mt)
        ab[mt] = A + (size_t)(m0 + mt * 16 + l16) * SD + quad * 8;

    floatx4 acc[4][4];
    const floatx4 vzero = {0.f, 0.f, 0.f, 0.f};
#pragma unroll
    for (int mt = 0; mt < 4; ++mt)
#pragma unroll
        for (int nt = 0; nt < 4; ++nt) acc[mt][nt] = vzero;

    for (int kc = 0; kc < SD / 32; ++kc) {
        const int k0 = kc * 32;
        // all 4 waves cooperatively stage the shared B tile (rows w*16..w*16+15)
        gload_lds16(B + (size_t)(n0 + w * 16 + r4) * SD + k0 + srcc * 8,
                    &ldsB[(size_t)(w * 16) * 32]);
        short8 afr[4];
#pragma unroll
        for (int mt = 0; mt < 4; ++mt)
            afr[mt] = *reinterpret_cast<const short8*>(ab[mt] + k0);
        __syncthreads();

        short8 bfr[4];
#pragma unroll
        for (int nt = 0; nt < 4; ++nt)
            bfr[nt] = *reinterpret_cast<const short8*>(
                &ldsB[(nt * 16 + l16) * 32 + (quad ^ swz) * 8]);
#pragma unroll
        for (int mt = 0; mt < 4; ++mt)
#pragma unroll
            for (int nt = 0; nt < 4; ++nt)
                acc[mt][nt] = __builtin_amdgcn_mfma_f32_16x16x32_bf16(
                    afr[mt], bfr[nt], acc[mt][nt], 0, 0, 0);
        __syncthreads();
    }

#pragma unroll
    for (int mt = 0; mt < 4; ++mt) {
        const int mb = m0 + mt * 16 + quad * 4;
        const floatx4 bz = *reinterpret_cast<const floatx4*>(bp2 + mb);
#pragma unroll
        for (int nt = 0; nt < 4; ++nt)
#pragma unroll
            for (int j = 0; j < 4; ++j) acc[mt][nt][j] += bz[j];
    }

#pragma unroll
    for (int nt = 0; nt < 4; ++nt) {
        float lm = -1e30f;
#pragma unroll
        for (int mt = 0; mt < 4; ++mt)
#pragma unroll
            for (int j = 0; j < 4; ++j) lm = fmaxf(lm, acc[mt][nt][j]);
        redmax[nt * 256 + l16 * 16 + w * 4 + quad] = lm;
    }
    __syncthreads();

    float lse[4];
#pragma unroll
    for (int nt = 0; nt < 4; ++nt) {
        float gm = -1e30f;
#pragma unroll
        for (int i = 0; i < 16; ++i) gm = fmaxf(gm, redmax[nt * 256 + l16 * 16 + i]);
        float ls = 0.f;
#pragma unroll
        for (int mt = 0; mt < 4; ++mt)
#pragma unroll
            for (int j = 0; j < 4; ++j) ls += __expf(acc[mt][nt][j] - gm);
        redsum[nt * 256 + l16 * 16 + w * 4 + quad] = ls;
        lse[nt] = gm;
    }
    __syncthreads();

#pragma unroll
    for (int nt = 0; nt < 4; ++nt) {
        float tot = 0.f;
#pragma unroll
        for (int i = 0; i < 16; ++i) tot += redsum[nt * 256 + l16 * 16 + i];
        lse[nt] = lse[nt] + __logf(tot);
    }

#pragma unroll
    for (int mt = 0; mt < 4; ++mt) {
        const int mb = m0 + mt * 16 + quad * 4;
#pragma unroll
        for (int nt = 0; nt < 4; ++nt) {
            const int t = n0 + nt * 16 + l16;
#pragma unroll
            for (int j = 0; j < 4; ++j)
                out[(size_t)(mb + j) * T_LEN + t] = acc[mt][nt][j] - lse[nt];
        }
    }
}

extern "C" void kernel_launch(void* const* d_in, const int* in_sizes, int n_in,
                              void* d_out, int out_size, void* d_ws, size_t ws_size,
                              hipStream_t stream)
{
    (void)in_sizes; (void)n_in; (void)out_size; (void)ws_size;
    const float* x     = (const float*)d_in[0];
    const float* Wc    = (const float*)d_in[1];
    const float* bc    = (const float*)d_in[2];
    const float* Wt    = (const float*)d_in[3];
    const float* bt    = (const float*)d_in[4];
    const float* Ws    = (const float*)d_in[5];
    const float* bs    = (const float*)d_in[6];
    const float* Wskip = (const float*)d_in[7];
    const float* bskip = (const float*)d_in[8];
    const float* Wd    = (const float*)d_in[9];
    const float* bd    = (const float*)d_in[10];
    const float* Wp1   = (const float*)d_in[11];
    const float* bp1   = (const float*)d_in[12];
    const float* Wp2   = (const float*)d_in[13];
    const float* bp2   = (const float*)d_in[14];
    float* out = (float*)d_out;

    char* p = (char*)d_ws;
    unsigned short* Gt = (unsigned short*)p;    p += (size_t)T_LEN * KTOT * 2;   // 226.5 MB
    unsigned short* ht = (unsigned short*)p;    p += (size_t)T_LEN * SD * 2;     // 134 MB
    unsigned short* Wcomb = (unsigned short*)p; p += (size_t)SD * KTOT * 2;
    unsigned short* Wp2b = (unsigned short*)p;  p += (size_t)QD * SD * 2;
    unsigned short* Wg = (unsigned short*)p;    p += (size_t)NL * 64 * 96 * 2;
    unsigned short* Wdb = (unsigned short*)p;   p += (size_t)NL * RD * RD * 2;
    float* hbias = (float*)p;                   p += (size_t)SD * 4;

    // x buffers alias the ht region (dead before gemm1 writes ht)
    char* q = (char*)ht;
    float* xa = (float*)q;                      q += (size_t)T_LEN * RD * 4;
    float* xb = (float*)q;                      q += (size_t)T_LEN * RD * 4;
    unsigned short* xba = (unsigned short*)q;   q += (size_t)T_LEN * RD * 2;
    unsigned short* xbb = (unsigned short*)q;   q += (size_t)T_LEN * RD * 2;

    k_wcomb<<<(SD * KTOT + 255) / 256, 256, 0, stream>>>(Wp1, Wskip, Wcomb);
    k_hbias<<<1, 512, 0, stream>>>(Wp1, bp1, bskip, hbias);
    k_cvt<<<(QD * SD + 255) / 256, 256, 0, stream>>>(Wp2, Wp2b, QD * SD);
    {
        const int nprep = NL * 64 * 96 + NL * RD * RD;
        k_wprep<<<(nprep + 255) / 256, 256, 0, stream>>>(Wt, Ws, Wd, Wg, Wdb);
    }
    k_conv_init<<<T_LEN / 256, 256, 0, stream>>>(x, Wc, bc, xa, xba);

    static const int dil[NL] = {1, 2, 4, 8, 16, 32, 64, 128, 256,
                                1, 2, 4, 8, 16, 32, 64, 128, 256,
                                1, 2, 4, 8, 16, 32, 64, 128, 256};
    const float* cur = xa;
    const unsigned short* curb = xba;
    float* nxt = xb;
    unsigned short* nxtb = xbb;
    for (int i = 0; i < NL; ++i) {
        k_layer_mfma<<<T_LEN / 128, 256, 0, stream>>>(
            cur, curb, nxt, nxtb, Gt,
            Wg + (size_t)i * 64 * 96,
            Wdb + (size_t)i * RD * RD,
            bt + (size_t)i * RD,
            bs + (size_t)i * RD,
            bd + (size_t)i * RD,
            dil[i], i);
        float* tf = (float*)cur; cur = nxt; nxt = tf;
        unsigned short* tb = (unsigned short*)curb; curb = nxtb; nxtb = tb;
    }

    k_gemm1<<<4 * (T_LEN / 128), 256, 0, stream>>>(Wcomb, Gt, hbias, ht);
    k_gemm2_lsm<<<T_LEN / 64, 256, 0, stream>>>(Wp2b, ht, bp2, out);
}

// Round 6
// 1056.216 us; speedup vs baseline: 2.9225x; 1.0470x over previous
//
#include <hip/hip_runtime.h>

#define T_LEN 131072
#define RD 32
#define SD 512
#define QD 256
#define NL 27
#define KTOT (NL * RD)   // 864

typedef __attribute__((ext_vector_type(8))) short short8;
typedef __attribute__((ext_vector_type(4))) float floatx4;

__device__ __forceinline__ unsigned short f2bf(float f) {
    union { float f; unsigned int i; } v; v.f = f;
    unsigned int r = v.i + 0x7fffu + ((v.i >> 16) & 1u);  // RNE
    return (unsigned short)(r >> 16);
}

__device__ __forceinline__ void gload_lds16(const void* g, void* l) {
    __builtin_amdgcn_global_load_lds(
        (const __attribute__((address_space(1))) unsigned int*)g,
        (__attribute__((address_space(3))) unsigned int*)l, 16, 0, 0);
}

// ---------------- initial conv: [1,T] -> [T][32] fp32 + bf16 copies ----------------
__global__ __launch_bounds__(256)
void k_conv_init(const float* __restrict__ x, const float* __restrict__ Wc,
                 const float* __restrict__ bc, float* __restrict__ xout,
                 unsigned short* __restrict__ xoutb)
{
    const int t = blockIdx.x * 256 + threadIdx.x;
    const float xm = (t > 0) ? x[t - 1] : 0.f;
    const float x0 = x[t];
    const float xp = (t < T_LEN - 1) ? x[t + 1] : 0.f;
    float* row = xout + (size_t)t * RD;
    unsigned short* rowb = xoutb + (size_t)t * RD;
#pragma unroll
    for (int o = 0; o < RD; ++o) {
        const float v = bc[o] + Wc[o * 3 + 0] * xm + Wc[o * 3 + 1] * x0 + Wc[o * 3 + 2] * xp;
        row[o] = v;
        rowb[o] = f2bf(v);
    }
}

// ---------------- weight prep ----------------
__global__ __launch_bounds__(256)
void k_wprep(const float* __restrict__ Wt, const float* __restrict__ Ws,
             const float* __restrict__ Wd,
             unsigned short* __restrict__ Wg, unsigned short* __restrict__ Wdb)
{
    const int idx = blockIdx.x * 256 + threadIdx.x;
    const int n1 = NL * 64 * 96;
    const int n2 = NL * RD * RD;
    if (idx < n1) {
        const int l = idx / (64 * 96);
        const int rem = idx % (64 * 96);
        const int m = rem / 96;
        const int k = rem % 96;
        const int j = k / 32;
        const int c = k % 32;
        float v;
        if (m < 32) v = Wt[(((size_t)l * RD + m) * RD + c) * 3 + j];
        else        v = Ws[(((size_t)l * RD + (m - 32)) * RD + c) * 3 + j];
        Wg[idx] = f2bf(v);
    } else if (idx < n1 + n2) {
        const int i2 = idx - n1;
        Wdb[i2] = f2bf(Wd[i2]);
    }
}

// ---------------- one residual layer via MFMA, 128 t per block ----------------
__global__ __launch_bounds__(256)
void k_layer_mfma(const float* __restrict__ xin, const unsigned short* __restrict__ xinb,
                  float* __restrict__ xout, unsigned short* __restrict__ xoutb,
                  unsigned short* __restrict__ Gt,
                  const unsigned short* __restrict__ Wg,   // [64][96] bf16
                  const unsigned short* __restrict__ Wdb,  // [32][32] bf16
                  const float* __restrict__ bt, const float* __restrict__ bs,
                  const float* __restrict__ bd, int d, int layer)
{
    __shared__ unsigned short gtile[128 * 32];  // 8 KB
    const int tid = threadIdx.x;
    const int lane = tid & 63;
    const int w = tid >> 6;
    const int quad = lane >> 4;
    const int l16 = lane & 15;
    const int tbase = blockIdx.x * 128 + w * 32;

    short8 afr[3][4];
#pragma unroll
    for (int j = 0; j < 3; ++j)
#pragma unroll
        for (int mt = 0; mt < 4; ++mt)
            afr[j][mt] = *reinterpret_cast<const short8*>(
                Wg + (size_t)(mt * 16 + l16) * 96 + j * 32 + quad * 8);

    floatx4 acc[4][2];
    const floatx4 vzero = {0.f, 0.f, 0.f, 0.f};
#pragma unroll
    for (int mt = 0; mt < 4; ++mt)
#pragma unroll
        for (int nt = 0; nt < 2; ++nt) acc[mt][nt] = vzero;

#pragma unroll
    for (int nt = 0; nt < 2; ++nt) {
        const int t = tbase + nt * 16 + l16;
#pragma unroll
        for (int j = 0; j < 3; ++j) {
            const int tt = t + (j - 1) * d;
            short8 b;
            if (tt >= 0 && tt < T_LEN) {
                b = *reinterpret_cast<const short8*>(xinb + (size_t)tt * RD + quad * 8);
            } else {
#pragma unroll
                for (int i = 0; i < 8; ++i) b[i] = 0;
            }
#pragma unroll
            for (int mt = 0; mt < 4; ++mt)
                acc[mt][nt] = __builtin_amdgcn_mfma_f32_16x16x32_bf16(afr[j][mt], b, acc[mt][nt], 0, 0, 0);
        }
    }

#pragma unroll
    for (int nt = 0; nt < 2; ++nt) {
        const int t = tbase + nt * 16 + l16;
        const int tloc = w * 32 + nt * 16 + l16;
#pragma unroll
        for (int pair = 0; pair < 2; ++pair) {
            const floatx4 bt4 = *reinterpret_cast<const floatx4*>(bt + pair * 16 + quad * 4);
            const floatx4 bs4 = *reinterpret_cast<const floatx4*>(bs + pair * 16 + quad * 4);
            ushort4 u;
            unsigned short us[4];
#pragma unroll
            for (int r = 0; r < 4; ++r) {
                const float a1 = acc[pair][nt][r] + bt4[r];
                const float a2 = acc[2 + pair][nt][r] + bs4[r];
                const float th = 1.f - __fdividef(2.f, __expf(2.f * a1) + 1.f);
                const float sg = __fdividef(1.f, 1.f + __expf(-a2));
                us[r] = f2bf(th * sg);
            }
            u.x = us[0]; u.y = us[1]; u.z = us[2]; u.w = us[3];
            const int cbase = pair * 16 + quad * 4;
            *reinterpret_cast<ushort4*>(&gtile[tloc * 32 + cbase]) = u;
            *reinterpret_cast<ushort4*>(Gt + (size_t)t * KTOT + layer * 32 + cbase) = u;
        }
    }

    __syncthreads();

    short8 ad[2];
#pragma unroll
    for (int mt = 0; mt < 2; ++mt)
        ad[mt] = *reinterpret_cast<const short8*>(Wdb + (size_t)(mt * 16 + l16) * 32 + quad * 8);

#pragma unroll
    for (int nt = 0; nt < 2; ++nt) {
        const int t = tbase + nt * 16 + l16;
        const int tloc = w * 32 + nt * 16 + l16;
        const short8 bg = *reinterpret_cast<const short8*>(&gtile[tloc * 32 + quad * 8]);
#pragma unroll
        for (int mt = 0; mt < 2; ++mt) {
            const floatx4 a2 = __builtin_amdgcn_mfma_f32_16x16x32_bf16(ad[mt], bg, vzero, 0, 0, 0);
            const int m = mt * 16 + quad * 4;
            const floatx4 bd4 = *reinterpret_cast<const floatx4*>(bd + m);
            const floatx4 xi = *reinterpret_cast<const floatx4*>(xin + (size_t)t * RD + m);
            floatx4 o;
            ushort4 ob;
            o[0] = a2[0] + bd4[0] + xi[0]; ob.x = f2bf(o[0]);
            o[1] = a2[1] + bd4[1] + xi[1]; ob.y = f2bf(o[1]);
            o[2] = a2[2] + bd4[2] + xi[2]; ob.z = f2bf(o[2]);
            o[3] = a2[3] + bd4[3] + xi[3]; ob.w = f2bf(o[3]);
            *reinterpret_cast<floatx4*>(xout + (size_t)t * RD + m) = o;
            *reinterpret_cast<ushort4*>(xoutb + (size_t)t * RD + m) = ob;
        }
    }
}

// ---------------- Wcomb ----------------
__global__ __launch_bounds__(256)
void k_wcomb(const float* __restrict__ Wp1, const float* __restrict__ Wskip,
             unsigned short* __restrict__ Wcomb)
{
    const int idx = blockIdx.x * 256 + threadIdx.x;
    if (idx >= SD * KTOT) return;
    const int m = idx / KTOT;
    const int k = idx % KTOT;
    const int l = k / RD;
    const int c = k % RD;
    const float* wp1r = Wp1 + (size_t)m * SD;
    const float* wsk = Wskip + (size_t)l * SD * RD + c;
    float acc = 0.f;
    for (int j = 0; j < SD; ++j) acc += wp1r[j] * wsk[(size_t)j * RD];
    Wcomb[idx] = f2bf(acc);
}

// ---------------- hbias ----------------
__global__ __launch_bounds__(512)
void k_hbias(const float* __restrict__ Wp1, const float* __restrict__ bp1,
             const float* __restrict__ bskip, float* __restrict__ hbias)
{
    __shared__ float sb[SD];
    const int tid = threadIdx.x;
    float s = 0.f;
    for (int l = 0; l < NL; ++l) s += bskip[l * SD + tid];
    sb[tid] = s;
    __syncthreads();
    float acc = bp1[tid];
    const float* r = Wp1 + (size_t)tid * SD;
    for (int j = 0; j < SD; ++j) acc += r[j] * sb[j];
    hbias[tid] = acc;
}

// ---------------- fp32 -> bf16 cast ----------------
__global__ __launch_bounds__(256)
void k_cvt(const float* __restrict__ src, unsigned short* __restrict__ dst, int n)
{
    const int i = blockIdx.x * 256 + threadIdx.x;
    if (i < n) dst[i] = f2bf(src[i]);
}

// ---------------- GEMM1: ht[t][m] = relu(hbias[m] + Wcomb@Gt) ----------------
// Dual-LDS m97 structure. XCD-sibling swizzle keeps the 4 m-siblings of one
// n-tile on one XCD (B L2-reuse). Chunk-permutation swizzle on BOTH A and B:
// slot (r,c) holds global chunk c ^ ((r>>1)&3); reader uses quad ^ ((l16>>1)&3).
__global__ __launch_bounds__(256)
void k_gemm1(const unsigned short* __restrict__ A,   // Wcomb [512][864] bf16
             const unsigned short* __restrict__ B,   // Gt [T][864] bf16
             const float* __restrict__ hbias,
             unsigned short* __restrict__ ht)        // [T][512] bf16
{
    __shared__ unsigned short ldsA[128 * 32];  // 8 KB
    __shared__ unsigned short ldsB[128 * 32];  // 8 KB
    const int tid = threadIdx.x;
    const int lane = tid & 63;
    const int w = tid >> 6;
    const int wm = w & 1;
    const int wn = w >> 1;
    const int quad = lane >> 4;
    const int l16 = lane & 15;

    const int g = blockIdx.x;
    const int m0 = ((g >> 3) & 3) * 128;
    const int n0 = ((g & 7) + 8 * (g >> 5)) * 128;

    const int r4 = lane >> 2;
    const int c4 = lane & 3;
    const int srcc = c4 ^ ((r4 >> 1) & 3);   // permuted global chunk
    const int swz = (l16 >> 1) & 3;          // reader-side key

    floatx4 acc[4][4];
    const floatx4 vzero = {0.f, 0.f, 0.f, 0.f};
#pragma unroll
    for (int mt = 0; mt < 4; ++mt)
#pragma unroll
        for (int nt = 0; nt < 4; ++nt) acc[mt][nt] = vzero;

    for (int kc = 0; kc < KTOT / 32; ++kc) {
        const int k0 = kc * 32;
#pragma unroll
        for (int c = 0; c < 2; ++c) {
            const int row = w * 32 + c * 16;
            gload_lds16(A + (size_t)(m0 + row + r4) * KTOT + k0 + srcc * 8,
                        &ldsA[(size_t)row * 32]);
            gload_lds16(B + (size_t)(n0 + row + r4) * KTOT + k0 + srcc * 8,
                        &ldsB[(size_t)row * 32]);
        }
        __syncthreads();

        short8 afr[4], bfr[4];
#pragma unroll
        for (int mt = 0; mt < 4; ++mt)
            afr[mt] = *reinterpret_cast<const short8*>(
                &ldsA[(wm * 64 + mt * 16 + l16) * 32 + (quad ^ swz) * 8]);
#pragma unroll
        for (int nt = 0; nt < 4; ++nt)
            bfr[nt] = *reinterpret_cast<const short8*>(
                &ldsB[(wn * 64 + nt * 16 + l16) * 32 + (quad ^ swz) * 8]);
#pragma unroll
        for (int mt = 0; mt < 4; ++mt)
#pragma unroll
            for (int nt = 0; nt < 4; ++nt)
                acc[mt][nt] = __builtin_amdgcn_mfma_f32_16x16x32_bf16(afr[mt], bfr[nt], acc[mt][nt], 0, 0, 0);
        __syncthreads();
    }

#pragma unroll
    for (int mt = 0; mt < 4; ++mt) {
        const int m = m0 + wm * 64 + mt * 16 + quad * 4;
        const floatx4 hb = *reinterpret_cast<const floatx4*>(hbias + m);
#pragma unroll
        for (int nt = 0; nt < 4; ++nt) {
            const int t = n0 + wn * 64 + nt * 16 + l16;
            ushort4 st;
            float v;
            v = acc[mt][nt][0] + hb[0]; st.x = f2bf(v > 0.f ? v : 0.f);
            v = acc[mt][nt][1] + hb[1]; st.y = f2bf(v > 0.f ? v : 0.f);
            v = acc[mt][nt][2] + hb[2]; st.z = f2bf(v > 0.f ? v : 0.f);
            v = acc[mt][nt][3] + hb[3]; st.w = f2bf(v > 0.f ? v : 0.f);
            *reinterpret_cast<ushort4*>(ht + (size_t)t * SD + m) = st;
        }
    }
}

// ---------------- GEMM2 + fused log_softmax, LDS-staged B ----------------
__global__ __launch_bounds__(256)
void k_gemm2_lsm(const unsigned short* __restrict__ A,  // Wp2b [256][512] bf16
                 const unsigned short* __restrict__ B,  // ht [T][512] bf16
                 const float* __restrict__ bp2,
                 float* __restrict__ out)               // [256][T] fp32
{
    __shared__ unsigned short ldsB[64 * 32];  // 4 KB
    __shared__ float redmax[4 * 16 * 16];
    __shared__ float redsum[4 * 16 * 16];
    const int tid = threadIdx.x;
    const int lane = tid & 63;
    const int w = tid >> 6;   // 0..3 = m-slice
    const int quad = lane >> 4;
    const int l16 = lane & 15;
    const int m0 = w * 64;
    const int n0 = blockIdx.x * 64;

    const int r4 = lane >> 2;
    const int c4 = lane & 3;
    const int srcc = c4 ^ ((r4 >> 1) & 3);
    const int swz = (l16 >> 1) & 3;

    const unsigned short* ab[4];
#pragma unroll
    for (int mt = 0; mt < 4; ++mt)
        ab[mt] = A + (size_t)(m0 + mt * 16 + l16) * SD + quad * 8;

    floatx4 acc[4][4];
    const floatx4 vzero = {0.f, 0.f, 0.f, 0.f};
#pragma unroll
    for (int mt = 0; mt < 4; ++mt)
#pragma unroll
        for (int nt = 0; nt < 4; ++nt) acc[mt][nt] = vzero;

    for (int kc = 0; kc < SD / 32; ++kc) {
        const int k0 = kc * 32;
        gload_lds16(B + (size_t)(n0 + w * 16 + r4) * SD + k0 + srcc * 8,
                    &ldsB[(size_t)(w * 16) * 32]);
        short8 afr[4];
#pragma unroll
        for (int mt = 0; mt < 4; ++mt)
            afr[mt] = *reinterpret_cast<const short8*>(ab[mt] + k0);
        __syncthreads();

        short8 bfr[4];
#pragma unroll
        for (int nt = 0; nt < 4; ++nt)
            bfr[nt] = *reinterpret_cast<const short8*>(
                &ldsB[(nt * 16 + l16) * 32 + (quad ^ swz) * 8]);
#pragma unroll
        for (int mt = 0; mt < 4; ++mt)
#pragma unroll
            for (int nt = 0; nt < 4; ++nt)
                acc[mt][nt] = __builtin_amdgcn_mfma_f32_16x16x32_bf16(
                    afr[mt], bfr[nt], acc[mt][nt], 0, 0, 0);
        __syncthreads();
    }

#pragma unroll
    for (int mt = 0; mt < 4; ++mt) {
        const int mb = m0 + mt * 16 + quad * 4;
        const floatx4 bz = *reinterpret_cast<const floatx4*>(bp2 + mb);
#pragma unroll
        for (int nt = 0; nt < 4; ++nt)
#pragma unroll
            for (int j = 0; j < 4; ++j) acc[mt][nt][j] += bz[j];
    }

#pragma unroll
    for (int nt = 0; nt < 4; ++nt) {
        float lm = -1e30f;
#pragma unroll
        for (int mt = 0; mt < 4; ++mt)
#pragma unroll
            for (int j = 0; j < 4; ++j) lm = fmaxf(lm, acc[mt][nt][j]);
        redmax[nt * 256 + l16 * 16 + w * 4 + quad] = lm;
    }
    __syncthreads();

    float lse[4];
#pragma unroll
    for (int nt = 0; nt < 4; ++nt) {
        float gm = -1e30f;
#pragma unroll
        for (int i = 0; i < 16; ++i) gm = fmaxf(gm, redmax[nt * 256 + l16 * 16 + i]);
        float ls = 0.f;
#pragma unroll
        for (int mt = 0; mt < 4; ++mt)
#pragma unroll
            for (int j = 0; j < 4; ++j) ls += __expf(acc[mt][nt][j] - gm);
        redsum[nt * 256 + l16 * 16 + w * 4 + quad] = ls;
        lse[nt] = gm;
    }
    __syncthreads();

#pragma unroll
    for (int nt = 0; nt < 4; ++nt) {
        float tot = 0.f;
#pragma unroll
        for (int i = 0; i < 16; ++i) tot += redsum[nt * 256 + l16 * 16 + i];
        lse[nt] = lse[nt] + __logf(tot);
    }

#pragma unroll
    for (int mt = 0; mt < 4; ++mt) {
        const int mb = m0 + mt * 16 + quad * 4;
#pragma unroll
        for (int nt = 0; nt < 4; ++nt) {
            const int t = n0 + nt * 16 + l16;
#pragma unroll
            for (int j = 0; j < 4; ++j)
                out[(size_t)(mb + j) * T_LEN + t] = acc[mt][nt][j] - lse[nt];
        }
    }
}

extern "C" void kernel_launch(void* const* d_in, const int* in_sizes, int n_in,
                              void* d_out, int out_size, void* d_ws, size_t ws_size,
                              hipStream_t stream)
{
    (void)in_sizes; (void)n_in; (void)out_size; (void)ws_size;
    const float* x     = (const float*)d_in[0];
    const float* Wc    = (const float*)d_in[1];
    const float* bc    = (const float*)d_in[2];
    const float* Wt    = (const float*)d_in[3];
    const float* bt    = (const float*)d_in[4];
    const float* Ws    = (const float*)d_in[5];
    const float* bs    = (const float*)d_in[6];
    const float* Wskip = (const float*)d_in[7];
    const float* bskip = (const float*)d_in[8];
    const float* Wd    = (const float*)d_in[9];
    const float* bd    = (const float*)d_in[10];
    const float* Wp1   = (const float*)d_in[11];
    const float* bp1   = (const float*)d_in[12];
    const float* Wp2   = (const float*)d_in[13];
    const float* bp2   = (const float*)d_in[14];
    float* out = (float*)d_out;

    char* p = (char*)d_ws;
    unsigned short* Gt = (unsigned short*)p;    p += (size_t)T_LEN * KTOT * 2;   // 226.5 MB
    unsigned short* ht = (unsigned short*)p;    p += (size_t)T_LEN * SD * 2;     // 134 MB
    unsigned short* Wcomb = (unsigned short*)p; p += (size_t)SD * KTOT * 2;
    unsigned short* Wp2b = (unsigned short*)p;  p += (size_t)QD * SD * 2;
    unsigned short* Wg = (unsigned short*)p;    p += (size_t)NL * 64 * 96 * 2;
    unsigned short* Wdb = (unsigned short*)p;   p += (size_t)NL * RD * RD * 2;
    float* hbias = (float*)p;                   p += (size_t)SD * 4;

    // x buffers alias the ht region (dead before gemm1 writes ht)
    char* q = (char*)ht;
    float* xa = (float*)q;                      q += (size_t)T_LEN * RD * 4;
    float* xb = (float*)q;                      q += (size_t)T_LEN * RD * 4;
    unsigned short* xba = (unsigned short*)q;   q += (size_t)T_LEN * RD * 2;
    unsigned short* xbb = (unsigned short*)q;   q += (size_t)T_LEN * RD * 2;

    k_wcomb<<<(SD * KTOT + 255) / 256, 256, 0, stream>>>(Wp1, Wskip, Wcomb);
    k_hbias<<<1, 512, 0, stream>>>(Wp1, bp1, bskip, hbias);
    k_cvt<<<(QD * SD + 255) / 256, 256, 0, stream>>>(Wp2, Wp2b, QD * SD);
    {
        const int nprep = NL * 64 * 96 + NL * RD * RD;
        k_wprep<<<(nprep + 255) / 256, 256, 0, stream>>>(Wt, Ws, Wd, Wg, Wdb);
    }
    k_conv_init<<<T_LEN / 256, 256, 0, stream>>>(x, Wc, bc, xa, xba);

    static const int dil[NL] = {1, 2, 4, 8, 16, 32, 64, 128, 256,
                                1, 2, 4, 8, 16, 32, 64, 128, 256,
                                1, 2, 4, 8, 16, 32, 64, 128, 256};
    const float* cur = xa;
    const unsigned short* curb = xba;
    float* nxt = xb;
    unsigned short* nxtb = xbb;
    for (int i = 0; i < NL; ++i) {
        k_layer_mfma<<<T_LEN / 128, 256, 0, stream>>>(
            cur, curb, nxt, nxtb, Gt,
            Wg + (size_t)i * 64 * 96,
            Wdb + (size_t)i * RD * RD,
            bt + (size_t)i * RD,
            bs + (size_t)i * RD,
            bd + (size_t)i * RD,
            dil[i], i);
        float* tf = (float*)cur; cur = nxt; nxt = tf;
        unsigned short* tb = (unsigned short*)curb; curb = nxtb; nxtb = tb;
    }

    k_gemm1<<<4 * (T_LEN / 128), 256, 0, stream>>>(Wcomb, Gt, hbias, ht);
    k_gemm2_lsm<<<T_LEN / 64, 256, 0, stream>>>(Wp2b, ht, bp2, out);
}